// Round 4
// baseline (624.627 us; speedup 1.0000x reference)
//
#include <hip/hip_runtime.h>
#include <cstdint>

// B=4, S=2048, E=1024, H=4, DH=256, DQ=256
typedef _Float16 f16;
typedef unsigned short u16;
typedef __attribute__((ext_vector_type(8))) _Float16 half8;
typedef __attribute__((ext_vector_type(4))) float f32x4;

#define MFMA_F16(a, b, c) __builtin_amdgcn_mfma_f32_16x16x32_f16(a, b, c, 0, 0, 0)

__device__ inline void stage16(const void* g, void* l) {
#if defined(__has_builtin) && __has_builtin(__builtin_amdgcn_global_load_lds)
  __builtin_amdgcn_global_load_lds(
      (const __attribute__((address_space(1))) unsigned*)g,
      (__attribute__((address_space(3))) unsigned*)l, 16, 0, 0);
#else
  *(int4*)l = *(const int4*)g;
#endif
}

// ======================= convert fp32 -> fp16 =======================
__global__ __launch_bounds__(256)
void conv_f16(const float* __restrict__ in, f16* __restrict__ out, int n) {
  int i = (blockIdx.x * 256 + threadIdx.x) * 8;
  if (i >= n) return;
  float4 a = *(const float4*)(in + i);
  float4 b = *(const float4*)(in + i + 4);
  half8 h;
  h[0] = (f16)a.x; h[1] = (f16)a.y; h[2] = (f16)a.z; h[3] = (f16)a.w;
  h[4] = (f16)b.x; h[5] = (f16)b.y; h[6] = (f16)b.z; h[7] = (f16)b.w;
  *(half8*)(out + i) = h;
}

// ======================= fp16 MFMA GEMM (unchanged) =======================
template<int EPI, int OUTF16>
__global__ __launch_bounds__(256, 2)
void gemm_f16(const f16* __restrict__ A, const f16* __restrict__ W,
              const float* __restrict__ bias, void* __restrict__ Cv,
              int N, int K, const float* __restrict__ aux) {
  __shared__ __align__(16) f16 lds[2][16384];
  const int tid = threadIdx.x;
  const int lane = tid & 63, w = tid >> 6;
  const int g = lane >> 4, lm = lane & 15;
  const int wr = w >> 1, wc = w & 1;
  const int m0 = blockIdx.y * 128, n0 = blockIdx.x * 128;

  const f16* src[8];
#pragma unroll
  for (int j = 0; j < 8; ++j) {
    int u = j * 256 + tid;
    if (u < 1024) {
      int row = u >> 3, s = u & 7;
      src[j] = A + (size_t)(m0 + row) * K + ((s ^ (row & 7)) << 3);
    } else {
      int v = u - 1024;
      int row = v >> 3, s = v & 7;
      src[j] = W + (size_t)(n0 + row) * K + ((s ^ (row & 7)) << 3);
    }
  }

  f32x4 acc[4][4];
#pragma unroll
  for (int mt = 0; mt < 4; ++mt)
#pragma unroll
    for (int nt = 0; nt < 4; ++nt) acc[mt][nt] = (f32x4){0.f, 0.f, 0.f, 0.f};

#pragma unroll
  for (int j = 0; j < 8; ++j) stage16(src[j], &lds[0][(j * 256 + tid) * 8]);
  __syncthreads();

  const int KT = K >> 6;
#pragma unroll 1
  for (int t = 0; t < KT; ++t) {
    const f16* bufA = lds[t & 1];
    const f16* bufB = bufA + 8192;
    if (t + 1 < KT) {
#pragma unroll
      for (int j = 0; j < 8; ++j) {
        src[j] += 64;
        stage16(src[j], &lds[(t + 1) & 1][(j * 256 + tid) * 8]);
      }
    }
#pragma unroll
    for (int ks = 0; ks < 2; ++ks) {
      half8 a[4], b[4];
#pragma unroll
      for (int mt = 0; mt < 4; ++mt) {
        int row = wr * 64 + mt * 16 + lm;
        a[mt] = *(const half8*)(bufA + row * 64 + (((ks * 4 + g) ^ (row & 7)) << 3));
      }
#pragma unroll
      for (int nt = 0; nt < 4; ++nt) {
        int row = wc * 64 + nt * 16 + lm;
        b[nt] = *(const half8*)(bufB + row * 64 + (((ks * 4 + g) ^ (row & 7)) << 3));
      }
#pragma unroll
      for (int mt = 0; mt < 4; ++mt)
#pragma unroll
        for (int nt = 0; nt < 4; ++nt)
          acc[mt][nt] = MFMA_F16(a[mt], b[nt], acc[mt][nt]);
    }
    __syncthreads();
  }

  const int crow = m0 + wr * 64 + g * 4;
  const int ccol = n0 + wc * 64 + lm;
#pragma unroll
  for (int nt = 0; nt < 4; ++nt) {
    float bb = bias[ccol + nt * 16];
#pragma unroll
    for (int mt = 0; mt < 4; ++mt) {
#pragma unroll
      for (int r = 0; r < 4; ++r) {
        size_t idx = (size_t)(crow + mt * 16 + r) * N + ccol + nt * 16;
        float v = acc[mt][nt][r] + bb;
        if (EPI == 1) v = 0.5f * v * (1.0f + erff(v * 0.70710678118654752f));
        if (EPI == 2) v = (0.9f * aux[idx] + 0.1f * v) * 2.0f;
        if (OUTF16) ((f16*)Cv)[idx] = (f16)v;
        else        ((float*)Cv)[idx] = v;
      }
    }
  }
}

// ======================= V transpose (unchanged) =======================
__global__ __launch_bounds__(256)
void vtrans(const f16* __restrict__ qkv, f16* __restrict__ Vt) {
  __shared__ unsigned vlds[64][65];
  const int tid = threadIdx.x;
  const int bh = blockIdx.x >> 5, st = blockIdx.x & 31;
  const int b = bh >> 2, h = bh & 3;
  const int s0 = st * 64;
  const u16* q16 = (const u16*)qkv;
  u16* v16 = (u16*)Vt;
#pragma unroll 1
  for (int dc = 0; dc < 4; ++dc) {
    __syncthreads();
#pragma unroll 1
    for (int i = 0; i < 16; ++i) {
      int idx = i * 256 + tid;
      int s = idx >> 6, dl = idx & 63;
      vlds[dl][s] = q16[(size_t)(b * 2048 + s0 + s) * 3072 + 2048 + h * 256 + dc * 64 + dl];
    }
    __syncthreads();
#pragma unroll 1
    for (int i = 0; i < 16; ++i) {
      int idx = i * 256 + tid;
      int dl = idx >> 6, s = idx & 63;
      v16[((size_t)bh * 256 + dc * 64 + dl) * 2048 + s0 + s] = (u16)vlds[dl][s];
    }
  }
}

// ======================= fp16 flash attention v2 =======================
// 4 waves x 16 q (BQ=64), TKV=32. K: global_load_lds double-buffered.
// V: single LDS buffer, reg-staged (issue-early / write-late). Defer-max softmax.
// LDS f16: K[2][32][256] @0, V[256][32] @16384, P 4x640 @24576 -> 54272 B (3 blocks/CU).
__global__ __launch_bounds__(256, 3)
void flash_f16(const f16* __restrict__ qkv, const f16* __restrict__ Vt,
               f16* __restrict__ attn) {
  __shared__ __align__(16) f16 lds[27136];
  const int tid = threadIdx.x;
  const int lane = tid & 63, w = tid >> 6;
  const int g = lane >> 4, lm = lane & 15;
  const int raw = blockIdx.x;
  const int bh = (raw & 7) * 2 + (raw >> 8);
  const int qt = (raw >> 3) & 31;
  const int b = bh >> 2, h = bh & 3;
  const int q0 = qt * 64 + w * 16;
  const float SC = 0.09016844005555896f;   // log2(e)/16

  half8 qf[8];
  {
    const f16* qp = qkv + (size_t)(b * 2048 + q0 + lm) * 3072 + h * 256 + g * 8;
#pragma unroll
    for (int c = 0; c < 8; ++c) qf[c] = *(const half8*)(qp + c * 32);
  }

  const f16* kbase = qkv + (size_t)b * 2048 * 3072 + 1024 + h * 256;
  const f16* vbase = Vt + (size_t)bh * 256 * 2048;
  int kofs[4], vofs[4];
#pragma unroll
  for (int j = 0; j < 4; ++j) {
    int u = j * 256 + tid;
    int kv = u >> 5, s = u & 31;
    kofs[j] = kv * 3072 + ((s ^ (kv & 7)) << 3);
    int d = u >> 2, sl = u & 3;
    vofs[j] = d * 2048 + ((sl ^ ((d >> 1) & 3)) << 3);
  }

  f32x4 o[16];
#pragma unroll
  for (int f = 0; f < 16; ++f) o[f] = (f32x4){0.f, 0.f, 0.f, 0.f};
  float m[4] = {-3e38f, -3e38f, -3e38f, -3e38f};
  float l[4] = {0.f, 0.f, 0.f, 0.f};

  // prologue: K0 -> buf0 (gload_lds), V0 -> regs -> LDS
  int4 vreg[4];
#pragma unroll
  for (int j = 0; j < 4; ++j) stage16(kbase + kofs[j], &lds[(j * 256 + tid) * 8]);
#pragma unroll
  for (int j = 0; j < 4; ++j) vreg[j] = *(const int4*)(vbase + vofs[j]);
#pragma unroll
  for (int j = 0; j < 4; ++j) *(int4*)&lds[16384 + (j * 256 + tid) * 8] = vreg[j];
  __syncthreads();

  f16* phf = &lds[24576 + w * 640];

#pragma unroll 1
  for (int t = 0; t < 64; ++t) {
    if (t < 63) {
      const int kt = (t + 1) * 98304, vt_ = (t + 1) * 32;
#pragma unroll
      for (int j = 0; j < 4; ++j)
        stage16(kbase + kofs[j] + kt, &lds[((t + 1) & 1) * 8192 + (j * 256 + tid) * 8]);
#pragma unroll
      for (int j = 0; j < 4; ++j) vreg[j] = *(const int4*)(vbase + vofs[j] + vt_);
    }
    const f16* kb = &lds[(t & 1) * 8192];
    const f16* vb = &lds[16384];

    // QK^T
    f32x4 s0 = {0.f, 0.f, 0.f, 0.f}, s1 = {0.f, 0.f, 0.f, 0.f};
#pragma unroll
    for (int c = 0; c < 8; ++c) {
      int slot = ((c * 4 + g) ^ (lm & 7)) << 3;
      half8 b0 = *(const half8*)(kb + lm * 256 + slot);
      half8 b1 = *(const half8*)(kb + (16 + lm) * 256 + slot);
      s0 = MFMA_F16(qf[c], b0, s0);
      s1 = MFMA_F16(qf[c], b1, s1);
    }

    // online softmax with defer-max (log2 domain)
    float a0[4], a1[4], mxv[4];
    bool ok = true;
#pragma unroll
    for (int r = 0; r < 4; ++r) {
      a0[r] = s0[r] * SC; a1[r] = s1[r] * SC;
      float mx = fmaxf(a0[r], a1[r]);
      mx = fmaxf(mx, __shfl_xor(mx, 1));
      mx = fmaxf(mx, __shfl_xor(mx, 2));
      mx = fmaxf(mx, __shfl_xor(mx, 4));
      mx = fmaxf(mx, __shfl_xor(mx, 8));
      mxv[r] = mx;
      ok = ok && (mx <= m[r] + 8.0f);
    }
    if (!__all(ok)) {
#pragma unroll
      for (int r = 0; r < 4; ++r) {
        float mn = fmaxf(m[r], mxv[r]);
        float corr = exp2f(m[r] - mn);
        m[r] = mn;
        l[r] *= corr;
#pragma unroll
        for (int f = 0; f < 16; ++f) o[f][r] *= corr;
      }
    }
#pragma unroll
    for (int r = 0; r < 4; ++r) {
      float p0 = exp2f(a0[r] - m[r]);
      float p1 = exp2f(a1[r] - m[r]);
      float rs = p0 + p1;
      rs += __shfl_xor(rs, 1);
      rs += __shfl_xor(rs, 2);
      rs += __shfl_xor(rs, 4);
      rs += __shfl_xor(rs, 8);
      l[r] += rs;
      phf[(g * 4 + r) * 40 + lm]      = (f16)p0;
      phf[(g * 4 + r) * 40 + 16 + lm] = (f16)p1;
    }
    half8 pa = *(const half8*)(phf + lm * 40 + g * 8);

    // PV
#pragma unroll
    for (int f = 0; f < 16; ++f) {
      int d = f * 16 + lm;
      half8 bv = *(const half8*)(vb + d * 32 + ((g ^ ((d >> 1) & 3)) << 3));
      o[f] = MFMA_F16(pa, bv, o[f]);
    }

    __syncthreads();           // all PV reads of V done; K prefetch drained
    if (t < 63) {
#pragma unroll
      for (int j = 0; j < 4; ++j) *(int4*)&lds[16384 + (j * 256 + tid) * 8] = vreg[j];
      __syncthreads();         // V[t+1] visible
    }
  }

  float inv[4];
#pragma unroll
  for (int r = 0; r < 4; ++r) inv[r] = 1.0f / l[r];
#pragma unroll
  for (int f = 0; f < 16; ++f)
#pragma unroll
    for (int r = 0; r < 4; ++r)
      attn[(size_t)(b * 2048 + q0 + g * 4 + r) * 1024 + h * 256 + f * 16 + lm] =
          (f16)(o[f][r] * inv[r]);
}

// ======================= Spectral attention v2: packed real FFTs =======================
__device__ inline float2 cmul(float2 a, float2 b) {
  return make_float2(a.x * b.x - a.y * b.y, a.x * b.y + a.y * b.x);
}
__device__ inline float2 cmulc(float2 a, float2 b) {   // a * conj(b)
  return make_float2(a.x * b.x + a.y * b.y, a.y * b.x - a.x * b.y);
}
__device__ inline void qcube(float2& w, float2& x, float2& y, float2& z, float2 f) {
  w = cmul(w, f); x = cmul(x, f); y = cmul(y, f); z = cmul(z, f);
  float2 a2 = cmul(w, w);
  float2 sx = cmul(x, x), sy = cmul(y, y), sz = cmul(z, z);
  float2 s = make_float2(sx.x + sy.x + sz.x, sx.y + sy.y + sz.y);
  float2 t3 = make_float2(a2.x - 3.f * s.x, a2.y - 3.f * s.y);
  float2 cf = make_float2(3.f * a2.x - s.x, 3.f * a2.y - s.y);
  w = cmul(w, t3); x = cmul(cf, x); y = cmul(cf, y); z = cmul(cf, z);
}

// block = (b, qd): channels c0..c0+3 packed as Z0 = c0 + i c1, Z1 = c2 + i c3.
__global__ __launch_bounds__(256)
void spectral2(const float* __restrict__ chol, const float* __restrict__ xin,
               float* __restrict__ outp) {
  __shared__ __align__(16) float2 Z[2][2048];   // 32 KB
  __shared__ float2 tw[1024];                   // 8 KB
  const int tid = threadIdx.x;
  const int b = blockIdx.x >> 8;
  const int qd = blockIdx.x & 255;
  const size_t c0 = (size_t)qd * 4;
  const float* cb = chol + (size_t)b * 2048 * 1024;

  for (int j = tid; j < 1024; j += 256) {
    float ang = -6.2831853071795864769f * (float)j * (1.0f / 2048.0f);
    float sv, cv; sincosf(ang, &sv, &cv);
    tw[j] = make_float2(cv, sv);
  }
  for (int s = tid; s < 2048; s += 256) {
    float4 v = *(const float4*)(cb + (size_t)s * 1024 + c0);
    Z[0][s] = make_float2(v.x, v.y);
    Z[1][s] = make_float2(v.z, v.w);
  }
  __syncthreads();

  // ---- forward DIF, LDS stages h=1024..16 ----
  for (int lh = 10; lh >= 4; --lh) {
    const int half = 1 << lh;
#pragma unroll 1
    for (int it = 0; it < 8; ++it) {
      int gg = it * 256 + tid;         // 2 arrays x 1024 butterflies
      int c = gg >> 10;
      int bf = gg & 1023;
      int j = bf & (half - 1);
      int base = ((bf >> lh) << (lh + 1)) | j;
      float2 a = Z[c][base];
      float2 bb = Z[c][base + half];
      float2 dif = make_float2(a.x - bb.x, a.y - bb.y);
      Z[c][base] = make_float2(a.x + bb.x, a.y + bb.y);
      Z[c][base + half] = cmul(dif, tw[j << (10 - lh)]);
    }
    __syncthreads();
  }

  // ---- forward DIF, register stages h=8,4,2,1 (16 consecutive elems/thread) ----
  {
    const int sel = tid >> 7;
    const int o = (tid & 127) * 16;
    float4* zp = (float4*)&Z[sel][o];
    float2 v[16];
#pragma unroll
    for (int i = 0; i < 8; ++i) {
      int j = (i + tid) & 7;           // rotate to spread banks
      float4 t4 = zp[j];
      v[2 * j]     = make_float2(t4.x, t4.y);
      v[2 * j + 1] = make_float2(t4.z, t4.w);
    }
#pragma unroll
    for (int j = 0; j < 8; ++j) {      // h=8
      float2 a = v[j], bb = v[j + 8];
      v[j] = make_float2(a.x + bb.x, a.y + bb.y);
      v[j + 8] = cmul(make_float2(a.x - bb.x, a.y - bb.y), tw[j * 128]);
    }
#pragma unroll
    for (int gb = 0; gb < 16; gb += 8)   // h=4
#pragma unroll
      for (int j = 0; j < 4; ++j) {
        float2 a = v[gb + j], bb = v[gb + j + 4];
        v[gb + j] = make_float2(a.x + bb.x, a.y + bb.y);
        v[gb + j + 4] = cmul(make_float2(a.x - bb.x, a.y - bb.y), tw[j * 256]);
      }
#pragma unroll
    for (int gb = 0; gb < 16; gb += 4)   // h=2
#pragma unroll
      for (int j = 0; j < 2; ++j) {
        float2 a = v[gb + j], bb = v[gb + j + 2];
        v[gb + j] = make_float2(a.x + bb.x, a.y + bb.y);
        v[gb + j + 2] = cmul(make_float2(a.x - bb.x, a.y - bb.y), tw[j * 512]);
      }
#pragma unroll
    for (int gb = 0; gb < 16; gb += 2) { // h=1
      float2 a = v[gb], bb = v[gb + 1];
      v[gb] = make_float2(a.x + bb.x, a.y + bb.y);
      v[gb + 1] = make_float2(a.x - bb.x, a.y - bb.y);
    }
#pragma unroll
    for (int i = 0; i < 8; ++i) {
      int j = (i + tid) & 7;
      zp[j] = make_float4(v[2 * j].x, v[2 * j].y, v[2 * j + 1].x, v[2 * j + 1].y);
    }
  }
  __syncthreads();

  // ---- middle: untangle pairs (k, N-k), filter, quaternion cube, retangle ----
#pragma unroll 1
  for (int it = 0; it < 4; ++it) {
    int jj = it * 256 + tid;
    int nrep = (jj == 0) ? 2 : 1;
#pragma unroll 1
    for (int rep = 0; rep < nrep; ++rep) {
      int k  = (jj == 0) ? (rep ? 1024 : 0) : jj;
      int kn = (jj == 0) ? k : 2048 - jj;
      int p  = __brev((unsigned)k) >> 21;
      int pp = __brev((unsigned)kn) >> 21;
      float2 z0p = Z[0][p], z0q = Z[0][pp];
      float2 z1p = Z[1][p], z1q = Z[1][pp];
      // untangle: spectra of the 4 real channels at k and kn
      float2 wk = make_float2(0.5f * (z0p.x + z0q.x), 0.5f * (z0p.y - z0q.y));
      float2 xk = make_float2(0.5f * (z0p.y + z0q.y), 0.5f * (z0q.x - z0p.x));
      float2 yk = make_float2(0.5f * (z1p.x + z1q.x), 0.5f * (z1p.y - z1q.y));
      float2 zk = make_float2(0.5f * (z1p.y + z1q.y), 0.5f * (z1q.x - z1p.x));
      float2 wn = make_float2(0.5f * (z0q.x + z0p.x), 0.5f * (z0q.y - z0p.y));
      float2 xn = make_float2(0.5f * (z0q.y + z0p.y), 0.5f * (z0p.x - z0q.x));
      float2 yn = make_float2(0.5f * (z1q.x + z1p.x), 0.5f * (z1q.y - z1p.y));
      float2 zn = make_float2(0.5f * (z1q.y + z1p.y), 0.5f * (z1p.x - z1q.x));
      // filters
      float sk, ck, sn, cn;
      sincosf(1.5f * atanf(logf((float)k + 1e-10f)), &sk, &ck);
      sincosf(1.5f * atanf(logf((float)kn + 1e-10f)), &sn, &cn);
      qcube(wk, xk, yk, zk, make_float2(ck, sk));
      qcube(wn, xn, yn, zn, make_float2(cn, sn));
      // retangle: B = H(W) + i H(X); Hermitian parts so ifft gives packed reals
      Z[0][p]  = make_float2(0.5f * (wk.x + wn.x) - 0.5f * (xk.y - xn.y),
                             0.5f * (wk.y - wn.y) + 0.5f * (xk.x + xn.x));
      Z[0][pp] = make_float2(0.5f * (wn.x + wk.x) - 0.5f * (xn.y - xk.y),
                             0.5f * (wn.y - wk.y) + 0.5f * (xn.x + xk.x));
      Z[1][p]  = make_float2(0.5f * (yk.x + yn.x) - 0.5f * (zk.y - zn.y),
                             0.5f * (yk.y - yn.y) + 0.5f * (zk.x + zn.x));
      Z[1][pp] = make_float2(0.5f * (yn.x + yk.x) - 0.5f * (zn.y - zk.y),
                             0.5f * (yn.y - yk.y) + 0.5f * (zn.x + zk.x));
    }
  }
  __syncthreads();

  // ---- inverse DIT, register stages h=1,2,4,8 ----
  {
    const int sel = tid >> 7;
    const int o = (tid & 127) * 16;
    float4* zp = (float4*)&Z[sel][o];
    float2 v[16];
#pragma unroll
    for (int i = 0; i < 8; ++i) {
      int j = (i + tid) & 7;
      float4 t4 = zp[j];
      v[2 * j]     = make_float2(t4.x, t4.y);
      v[2 * j + 1] = make_float2(t4.z, t4.w);
    }
#pragma unroll
    for (int gb = 0; gb < 16; gb += 2) { // h=1
      float2 a = v[gb], bb = v[gb + 1];
      v[gb] = make_float2(a.x + bb.x, a.y + bb.y);
      v[gb + 1] = make_float2(a.x - bb.x, a.y - bb.y);
    }
#pragma unroll
    for (int gb = 0; gb < 16; gb += 4)   // h=2
#pragma unroll
      for (int j = 0; j < 2; ++j) {
        float2 a = v[gb + j], bw = cmulc(v[gb + j + 2], tw[j * 512]);
        v[gb + j] = make_float2(a.x + bw.x, a.y + bw.y);
        v[gb + j + 2] = make_float2(a.x - bw.x, a.y - bw.y);
      }
#pragma unroll
    for (int gb = 0; gb < 16; gb += 8)   // h=4
#pragma unroll
      for (int j = 0; j < 4; ++j) {
        float2 a = v[gb + j], bw = cmulc(v[gb + j + 4], tw[j * 256]);
        v[gb + j] = make_float2(a.x + bw.x, a.y + bw.y);
        v[gb + j + 4] = make_float2(a.x - bw.x, a.y - bw.y);
      }
#pragma unroll
    for (int j = 0; j < 8; ++j) {        // h=8
      float2 a = v[j], bw = cmulc(v[j + 8], tw[j * 128]);
      v[j] = make_float2(a.x + bw.x, a.y + bw.y);
      v[j + 8] = make_float2(a.x - bw.x, a.y - bw.y);
    }
#pragma unroll
    for (int i = 0; i < 8; ++i) {
      int j = (i + tid) & 7;
      zp[j] = make_float4(v[2 * j].x, v[2 * j].y, v[2 * j + 1].x, v[2 * j + 1].y);
    }
  }
  __syncthreads();

  // ---- inverse DIT, LDS stages h=16..1024 ----
  for (int lh = 4; lh <= 10; ++lh) {
    const int half = 1 << lh;
#pragma unroll 1
    for (int it = 0; it < 8; ++it) {
      int gg = it * 256 + tid;
      int c = gg >> 10;
      int bf = gg & 1023;
      int j = bf & (half - 1);
      int base = ((bf >> lh) << (lh + 1)) | j;
      float2 a = Z[c][base];
      float2 bw = cmulc(Z[c][base + half], tw[j << (10 - lh)]);
      Z[c][base] = make_float2(a.x + bw.x, a.y + bw.y);
      Z[c][base + half] = make_float2(a.x - bw.x, a.y - bw.y);
    }
    __syncthreads();
  }

  const float* xb = xin + (size_t)b * 2048 * 1024;
  float* ob = outp + (size_t)b * 2048 * 1024;
  const float inv = 1.0f / 2048.0f;
  for (int s = tid; s < 2048; s += 256) {
    float4 xv = *(const float4*)(xb + (size_t)s * 1024 + c0);
    float2 r0 = Z[0][s], r1 = Z[1][s];
    float4 o;
    o.x = xv.x * r0.x * inv;
    o.y = xv.y * r0.y * inv;
    o.z = xv.z * r1.x * inv;
    o.w = xv.w * r1.y * inv;
    *(float4*)(ob + (size_t)s * 1024 + c0) = o;
  }
}

// ======================= launch =======================
extern "C" void kernel_launch(void* const* d_in, const int* in_sizes, int n_in,
                              void* d_out, int out_size, void* d_ws, size_t ws_size,
                              hipStream_t stream) {
  const float* x    = (const float*)d_in[0];
  const float* wqkv = (const float*)d_in[1];
  const float* bqkv = (const float*)d_in[2];
  const float* wout = (const float*)d_in[3];
  const float* bout = (const float*)d_in[4];
  const float* w1   = (const float*)d_in[5];
  const float* b1   = (const float*)d_in[6];
  const float* w2   = (const float*)d_in[7];
  const float* b2   = (const float*)d_in[8];
  float* out = (float*)d_out;
  char* wsb = (char*)d_ws;
  const size_t MB = 1048576;

  f16*   xf    = (f16*)(wsb);
  f16*   wqf   = (f16*)(wsb + 16 * MB);
  f16*   wof   = (f16*)(wsb + 22 * MB);
  f16*   w1f   = (f16*)(wsb + 24 * MB);
  f16*   w2f   = (f16*)(wsb + 26 * MB);
  f16*   qkvF  = (f16*)(wsb + 28 * MB);
  f16*   VtF   = (f16*)(wsb + 76 * MB);
  f16*   attnF = (f16*)(wsb + 92 * MB);
  float* nico  = (float*)(wsb + 108 * MB);
  f16*   hF    = (f16*)(wsb + 140 * MB);
  float* chol  = (float*)(wsb + 156 * MB);

  conv_f16<<<4096, 256, 0, stream>>>(x, xf, 8388608);
  conv_f16<<<1536, 256, 0, stream>>>(wqkv, wqf, 3145728);
  conv_f16<<<512, 256, 0, stream>>>(wout, wof, 1048576);
  conv_f16<<<512, 256, 0, stream>>>(w1, w1f, 1048576);
  conv_f16<<<512, 256, 0, stream>>>(w2, w2f, 1048576);

  gemm_f16<0, 1><<<dim3(24, 64), 256, 0, stream>>>(xf, wqf, bqkv, qkvF, 3072, 1024, nullptr);
  vtrans<<<512, 256, 0, stream>>>(qkvF, VtF);
  flash_f16<<<512, 256, 0, stream>>>(qkvF, VtF, attnF);
  gemm_f16<0, 0><<<dim3(8, 64), 256, 0, stream>>>(attnF, wof, bout, nico, 1024, 1024, nullptr);
  gemm_f16<1, 1><<<dim3(8, 64), 256, 0, stream>>>(xf, w1f, b1, hF, 1024, 1024, nullptr);
  gemm_f16<2, 0><<<dim3(8, 64), 256, 0, stream>>>(hF, w2f, b2, chol, 1024, 1024, nico);
  spectral2<<<1024, 256, 0, stream>>>(chol, x, out);
}

// Round 5
// 476.559 us; speedup vs baseline: 1.3107x; 1.3107x over previous
//
#include <hip/hip_runtime.h>
#include <cstdint>

// B=4, S=2048, E=1024, H=4, DH=256, DQ=256
typedef _Float16 f16;
typedef unsigned short u16;
typedef __attribute__((ext_vector_type(8))) _Float16 half8;
typedef __attribute__((ext_vector_type(4))) float f32x4;

#define MFMA_F16(a, b, c) __builtin_amdgcn_mfma_f32_16x16x32_f16(a, b, c, 0, 0, 0)

// counted-vmcnt barrier primitives (T3/T4): never drain vmcnt to 0 in the main loop
#define WAITVM8() asm volatile("s_waitcnt vmcnt(8)" ::: "memory")
#define WAITVM0() asm volatile("s_waitcnt vmcnt(0)" ::: "memory")
#define BARRIER() do { asm volatile("" ::: "memory"); __builtin_amdgcn_s_barrier(); \
                       asm volatile("" ::: "memory"); } while (0)

__device__ inline void stage16(const void* g, void* l) {
#if defined(__has_builtin) && __has_builtin(__builtin_amdgcn_global_load_lds)
  __builtin_amdgcn_global_load_lds(
      (const __attribute__((address_space(1))) unsigned*)g,
      (__attribute__((address_space(3))) unsigned*)l, 16, 0, 0);
#else
  *(int4*)l = *(const int4*)g;
#endif
}

// ======================= convert fp32 -> fp16 =======================
__global__ __launch_bounds__(256)
void conv_f16(const float* __restrict__ in, f16* __restrict__ out, int n) {
  int i = (blockIdx.x * 256 + threadIdx.x) * 8;
  if (i >= n) return;
  float4 a = *(const float4*)(in + i);
  float4 b = *(const float4*)(in + i + 4);
  half8 h;
  h[0] = (f16)a.x; h[1] = (f16)a.y; h[2] = (f16)a.z; h[3] = (f16)a.w;
  h[4] = (f16)b.x; h[5] = (f16)b.y; h[6] = (f16)b.z; h[7] = (f16)b.w;
  *(half8*)(out + i) = h;
}

// ======================= fp16 MFMA GEMM, counted-vmcnt 2-phase =======================
template<int EPI, int OUTF16>
__global__ __launch_bounds__(256, 2)
void gemm_f16(const f16* __restrict__ A, const f16* __restrict__ W,
              const float* __restrict__ bias, void* __restrict__ Cv,
              int N, int K, const float* __restrict__ aux) {
  __shared__ __align__(16) f16 lds[2][16384];
  const int tid = threadIdx.x;
  const int lane = tid & 63, w = tid >> 6;
  const int g = lane >> 4, lm = lane & 15;
  const int wr = w >> 1, wc = w & 1;
  const int m0 = blockIdx.y * 128, n0 = blockIdx.x * 128;

  const f16* src[8];
#pragma unroll
  for (int j = 0; j < 8; ++j) {
    int u = j * 256 + tid;
    if (u < 1024) {
      int row = u >> 3, s = u & 7;
      src[j] = A + (size_t)(m0 + row) * K + ((s ^ (row & 7)) << 3);
    } else {
      int v = u - 1024;
      int row = v >> 3, s = v & 7;
      src[j] = W + (size_t)(n0 + row) * K + ((s ^ (row & 7)) << 3);
    }
  }

  f32x4 acc[4][4];
#pragma unroll
  for (int mt = 0; mt < 4; ++mt)
#pragma unroll
    for (int nt = 0; nt < 4; ++nt) acc[mt][nt] = (f32x4){0.f, 0.f, 0.f, 0.f};

#pragma unroll
  for (int j = 0; j < 8; ++j) stage16(src[j], &lds[0][(j * 256 + tid) * 8]);
  __syncthreads();   // one-time full drain

  const int KT = K >> 6;
#pragma unroll 1
  for (int t = 0; t < KT; ++t) {
    const f16* bufA = lds[t & 1];
    const f16* bufB = bufA + 8192;
    if (t + 1 < KT) {
#pragma unroll
      for (int j = 0; j < 8; ++j) {
        src[j] += 64;
        stage16(src[j], &lds[(t + 1) & 1][(j * 256 + tid) * 8]);
      }
      WAITVM8();     // tile-t landed, tile-(t+1) still in flight
    } else {
      WAITVM0();
    }
    BARRIER();
#pragma unroll
    for (int ks = 0; ks < 2; ++ks) {
      half8 a[4], b[4];
#pragma unroll
      for (int mt = 0; mt < 4; ++mt) {
        int row = wr * 64 + mt * 16 + lm;
        a[mt] = *(const half8*)(bufA + row * 64 + (((ks * 4 + g) ^ (row & 7)) << 3));
      }
#pragma unroll
      for (int nt = 0; nt < 4; ++nt) {
        int row = wc * 64 + nt * 16 + lm;
        b[nt] = *(const half8*)(bufB + row * 64 + (((ks * 4 + g) ^ (row & 7)) << 3));
      }
#pragma unroll
      for (int mt = 0; mt < 4; ++mt)
#pragma unroll
        for (int nt = 0; nt < 4; ++nt)
          acc[mt][nt] = MFMA_F16(a[mt], b[nt], acc[mt][nt]);
    }
    BARRIER();       // all waves done reading buf[t&1]; next iter may overwrite
  }

  const int crow = m0 + wr * 64 + g * 4;
  const int ccol = n0 + wc * 64 + lm;
#pragma unroll
  for (int nt = 0; nt < 4; ++nt) {
    float bb = bias[ccol + nt * 16];
#pragma unroll
    for (int mt = 0; mt < 4; ++mt) {
#pragma unroll
      for (int r = 0; r < 4; ++r) {
        size_t idx = (size_t)(crow + mt * 16 + r) * N + ccol + nt * 16;
        float v = acc[mt][nt][r] + bb;
        if (EPI == 1) v = 0.5f * v * (1.0f + erff(v * 0.70710678118654752f));
        if (EPI == 2) v = (0.9f * aux[idx] + 0.1f * v) * 2.0f;
        if (OUTF16) ((f16*)Cv)[idx] = (f16)v;
        else        ((float*)Cv)[idx] = v;
      }
    }
  }
}

// ======================= V transpose (unchanged) =======================
__global__ __launch_bounds__(256)
void vtrans(const f16* __restrict__ qkv, f16* __restrict__ Vt) {
  __shared__ unsigned vlds[64][65];
  const int tid = threadIdx.x;
  const int bh = blockIdx.x >> 5, st = blockIdx.x & 31;
  const int b = bh >> 2, h = bh & 3;
  const int s0 = st * 64;
  const u16* q16 = (const u16*)qkv;
  u16* v16 = (u16*)Vt;
#pragma unroll 1
  for (int dc = 0; dc < 4; ++dc) {
    __syncthreads();
#pragma unroll 1
    for (int i = 0; i < 16; ++i) {
      int idx = i * 256 + tid;
      int s = idx >> 6, dl = idx & 63;
      vlds[dl][s] = q16[(size_t)(b * 2048 + s0 + s) * 3072 + 2048 + h * 256 + dc * 64 + dl];
    }
    __syncthreads();
#pragma unroll 1
    for (int i = 0; i < 16; ++i) {
      int idx = i * 256 + tid;
      int dl = idx >> 6, s = idx & 63;
      v16[((size_t)bh * 256 + dc * 64 + dl) * 2048 + s0 + s] = (u16)vlds[dl][s];
    }
  }
}

// ======================= fp16 flash attention v3: K/V dbuf + counted vmcnt =======================
// 4 waves x 16 q (BQ=64), TKV=32. K,V double-buffered via global_load_lds.
// LDS f16: K[2][32][256] @0, V[2][256][32] @16384, P 4x640 @32768 -> 70656 B (2 blocks/CU; grid=2/CU).
__global__ __launch_bounds__(256, 2)
void flash_f16(const f16* __restrict__ qkv, const f16* __restrict__ Vt,
               f16* __restrict__ attn) {
  __shared__ __align__(16) f16 lds[35328];
  const int tid = threadIdx.x;
  const int lane = tid & 63, w = tid >> 6;
  const int g = lane >> 4, lm = lane & 15;
  const int raw = blockIdx.x;
  const int bh = (raw & 7) * 2 + (raw >> 8);   // XCD-clustered (b,h)
  const int qt = (raw >> 3) & 31;
  const int b = bh >> 2, h = bh & 3;
  const int q0 = qt * 64 + w * 16;
  const float SC = 0.09016844005555896f;       // log2(e)/16

  half8 qf[8];
  {
    const f16* qp = qkv + (size_t)(b * 2048 + q0 + lm) * 3072 + h * 256 + g * 8;
#pragma unroll
    for (int c = 0; c < 8; ++c) qf[c] = *(const half8*)(qp + c * 32);
  }

  const f16* kbase = qkv + (size_t)b * 2048 * 3072 + 1024 + h * 256;
  const f16* vbase = Vt + (size_t)bh * 256 * 2048;
  int kofs[4], vofs[4];
#pragma unroll
  for (int j = 0; j < 4; ++j) {
    int u = j * 256 + tid;
    int kv = u >> 5, s = u & 31;
    kofs[j] = kv * 3072 + ((s ^ (kv & 7)) << 3);
    int d = u >> 2, sl = u & 3;
    vofs[j] = d * 2048 + ((sl ^ ((d >> 1) & 3)) << 3);
  }

  f32x4 o[16];
#pragma unroll
  for (int f = 0; f < 16; ++f) o[f] = (f32x4){0.f, 0.f, 0.f, 0.f};
  float m[4] = {-3e38f, -3e38f, -3e38f, -3e38f};
  float l[4] = {0.f, 0.f, 0.f, 0.f};

  // prologue: tile 0 -> buf0
#pragma unroll
  for (int j = 0; j < 4; ++j) {
    stage16(kbase + kofs[j], &lds[(j * 256 + tid) * 8]);
    stage16(vbase + vofs[j], &lds[16384 + (j * 256 + tid) * 8]);
  }
  __syncthreads();   // one-time full drain (also covers qf)

  f16* phf = &lds[32768 + w * 640];

#pragma unroll 1
  for (int t = 0; t < 64; ++t) {
    const int cb_ = t & 1;
    if (t < 63) {
      const int nb = cb_ ^ 1;
      const int kt = (t + 1) * 98304, vt_ = (t + 1) * 32;
#pragma unroll
      for (int j = 0; j < 4; ++j) {
        stage16(kbase + kofs[j] + kt, &lds[nb * 8192 + (j * 256 + tid) * 8]);
        stage16(vbase + vofs[j] + vt_, &lds[16384 + nb * 8192 + (j * 256 + tid) * 8]);
      }
      WAITVM8();   // tile-t landed; tile-(t+1)'s 8 loads stay in flight
    } else {
      WAITVM0();
    }
    BARRIER();

    const f16* kb = &lds[cb_ * 8192];
    const f16* vb = &lds[16384 + cb_ * 8192];

    // ---- QK^T ----
    f32x4 s0 = {0.f, 0.f, 0.f, 0.f}, s1 = {0.f, 0.f, 0.f, 0.f};
    __builtin_amdgcn_s_setprio(1);
#pragma unroll
    for (int c = 0; c < 8; ++c) {
      int slot = ((c * 4 + g) ^ (lm & 7)) << 3;
      half8 b0 = *(const half8*)(kb + lm * 256 + slot);
      half8 b1 = *(const half8*)(kb + (16 + lm) * 256 + slot);
      s0 = MFMA_F16(qf[c], b0, s0);
      s1 = MFMA_F16(qf[c], b1, s1);
    }
    __builtin_amdgcn_s_setprio(0);

    // ---- online softmax with defer-max (log2 domain) ----
    float a0[4], a1[4], mxv[4];
    bool ok = true;
#pragma unroll
    for (int r = 0; r < 4; ++r) {
      a0[r] = s0[r] * SC; a1[r] = s1[r] * SC;
      float mx = fmaxf(a0[r], a1[r]);
      mx = fmaxf(mx, __shfl_xor(mx, 1));
      mx = fmaxf(mx, __shfl_xor(mx, 2));
      mx = fmaxf(mx, __shfl_xor(mx, 4));
      mx = fmaxf(mx, __shfl_xor(mx, 8));
      mxv[r] = mx;
      ok = ok && (mx <= m[r] + 8.0f);
    }
    if (!__all(ok)) {
#pragma unroll
      for (int r = 0; r < 4; ++r) {
        float mn = fmaxf(m[r], mxv[r]);
        float corr = exp2f(m[r] - mn);
        m[r] = mn;
        l[r] *= corr;
#pragma unroll
        for (int f = 0; f < 16; ++f) o[f][r] *= corr;
      }
    }
#pragma unroll
    for (int r = 0; r < 4; ++r) {
      float p0 = exp2f(a0[r] - m[r]);
      float p1 = exp2f(a1[r] - m[r]);
      float rs = p0 + p1;
      rs += __shfl_xor(rs, 1);
      rs += __shfl_xor(rs, 2);
      rs += __shfl_xor(rs, 4);
      rs += __shfl_xor(rs, 8);
      l[r] += rs;
      phf[(g * 4 + r) * 40 + lm]      = (f16)p0;
      phf[(g * 4 + r) * 40 + 16 + lm] = (f16)p1;
    }
    half8 pa = *(const half8*)(phf + lm * 40 + g * 8);

    // ---- PV ----
    __builtin_amdgcn_s_setprio(1);
#pragma unroll
    for (int f = 0; f < 16; ++f) {
      int d = f * 16 + lm;
      half8 bv = *(const half8*)(vb + d * 32 + ((g ^ ((d >> 1) & 3)) << 3));
      o[f] = MFMA_F16(pa, bv, o[f]);
    }
    __builtin_amdgcn_s_setprio(0);

    BARRIER();   // all waves done reading buf[t&1]; no vmcnt drain
  }

  float inv[4];
#pragma unroll
  for (int r = 0; r < 4; ++r) inv[r] = 1.0f / l[r];
#pragma unroll
  for (int f = 0; f < 16; ++f)
#pragma unroll
    for (int r = 0; r < 4; ++r)
      attn[(size_t)(b * 2048 + q0 + g * 4 + r) * 1024 + h * 256 + f * 16 + lm] =
          (f16)(o[f][r] * inv[r]);
}

// ======================= Spectral v3: packed real FFTs, pure-LDS butterflies =======================
__device__ inline float2 cmul(float2 a, float2 b) {
  return make_float2(a.x * b.x - a.y * b.y, a.x * b.y + a.y * b.x);
}
__device__ inline float2 cmulc(float2 a, float2 b) {   // a * conj(b)
  return make_float2(a.x * b.x + a.y * b.y, a.y * b.x - a.x * b.y);
}
__device__ inline void qcube(float2& w, float2& x, float2& y, float2& z, float2 f) {
  w = cmul(w, f); x = cmul(x, f); y = cmul(y, f); z = cmul(z, f);
  float2 a2 = cmul(w, w);
  float2 sx = cmul(x, x), sy = cmul(y, y), sz = cmul(z, z);
  float2 s = make_float2(sx.x + sy.x + sz.x, sx.y + sy.y + sz.y);
  float2 t3 = make_float2(a2.x - 3.f * s.x, a2.y - 3.f * s.y);
  float2 cf = make_float2(3.f * a2.x - s.x, 3.f * a2.y - s.y);
  w = cmul(w, t3); x = cmul(cf, x); y = cmul(cf, y); z = cmul(cf, z);
}

// block = (b, qd): channels c0..c0+3 packed as Z0 = c0 + i c1, Z1 = c2 + i c3.
__global__ __launch_bounds__(256)
void spectral3(const float* __restrict__ chol, const float* __restrict__ xin,
               float* __restrict__ outp) {
  __shared__ __align__(16) float2 Z[2][2048];   // 32 KB
  __shared__ float2 tw[1024];                   // 8 KB -> 40 KB total, 4 blocks/CU
  const int tid = threadIdx.x;
  const int b = blockIdx.x >> 8;
  const int qd = blockIdx.x & 255;
  const size_t c0 = (size_t)qd * 4;
  const float* cb = chol + (size_t)b * 2048 * 1024;

  for (int j = tid; j < 1024; j += 256) {
    float ang = -6.2831853071795864769f * (float)j * (1.0f / 2048.0f);
    float sv, cv; sincosf(ang, &sv, &cv);
    tw[j] = make_float2(cv, sv);
  }
  for (int s = tid; s < 2048; s += 256) {
    float4 v = *(const float4*)(cb + (size_t)s * 1024 + c0);
    Z[0][s] = make_float2(v.x, v.y);
    Z[1][s] = make_float2(v.z, v.w);
  }
  __syncthreads();

  // ---- forward DIF: natural in -> bit-reversed out ----
  for (int lh = 10; lh >= 0; --lh) {
    const int half = 1 << lh;
#pragma unroll 1
    for (int it = 0; it < 8; ++it) {
      int gg = it * 256 + tid;          // 2 arrays x 1024 butterflies
      int c = gg >> 10;
      int bf = gg & 1023;
      int j = bf & (half - 1);
      int base = ((bf >> lh) << (lh + 1)) | j;
      float2 a = Z[c][base];
      float2 bb = Z[c][base + half];
      float2 dif = make_float2(a.x - bb.x, a.y - bb.y);
      Z[c][base] = make_float2(a.x + bb.x, a.y + bb.y);
      Z[c][base + half] = cmul(dif, tw[j << (10 - lh)]);
    }
    __syncthreads();
  }

  // ---- middle: untangle (k, N-k), filter, quaternion cube, retangle ----
#pragma unroll 1
  for (int it = 0; it < 4; ++it) {
    int jj = it * 256 + tid;
    int nrep = (jj == 0) ? 2 : 1;
#pragma unroll 1
    for (int rep = 0; rep < nrep; ++rep) {
      int k  = (jj == 0) ? (rep ? 1024 : 0) : jj;
      int kn = (jj == 0) ? k : 2048 - jj;
      int p  = __brev((unsigned)k) >> 21;
      int pp = __brev((unsigned)kn) >> 21;
      float2 z0p = Z[0][p], z0q = Z[0][pp];
      float2 z1p = Z[1][p], z1q = Z[1][pp];
      float2 wk = make_float2(0.5f * (z0p.x + z0q.x), 0.5f * (z0p.y - z0q.y));
      float2 xk = make_float2(0.5f * (z0p.y + z0q.y), 0.5f * (z0q.x - z0p.x));
      float2 yk = make_float2(0.5f * (z1p.x + z1q.x), 0.5f * (z1p.y - z1q.y));
      float2 zk = make_float2(0.5f * (z1p.y + z1q.y), 0.5f * (z1q.x - z1p.x));
      float2 wn = make_float2(0.5f * (z0q.x + z0p.x), 0.5f * (z0q.y - z0p.y));
      float2 xn = make_float2(0.5f * (z0q.y + z0p.y), 0.5f * (z0p.x - z0q.x));
      float2 yn = make_float2(0.5f * (z1q.x + z1p.x), 0.5f * (z1q.y - z1p.y));
      float2 zn = make_float2(0.5f * (z1q.y + z1p.y), 0.5f * (z1p.x - z1q.x));
      float sk, ck, sn, cn;
      sincosf(1.5f * atanf(logf((float)k + 1e-10f)), &sk, &ck);
      sincosf(1.5f * atanf(logf((float)kn + 1e-10f)), &sn, &cn);
      qcube(wk, xk, yk, zk, make_float2(ck, sk));
      qcube(wn, xn, yn, zn, make_float2(cn, sn));
      Z[0][p]  = make_float2(0.5f * (wk.x + wn.x) - 0.5f * (xk.y - xn.y),
                             0.5f * (wk.y - wn.y) + 0.5f * (xk.x + xn.x));
      Z[0][pp] = make_float2(0.5f * (wn.x + wk.x) - 0.5f * (xn.y - xk.y),
                             0.5f * (wn.y - wk.y) + 0.5f * (xn.x + xk.x));
      Z[1][p]  = make_float2(0.5f * (yk.x + yn.x) - 0.5f * (zk.y - zn.y),
                             0.5f * (yk.y - yn.y) + 0.5f * (zk.x + zn.x));
      Z[1][pp] = make_float2(0.5f * (yn.x + yk.x) - 0.5f * (zn.y - zk.y),
                             0.5f * (yn.y - yk.y) + 0.5f * (zn.x + zk.x));
    }
  }
  __syncthreads();

  // ---- inverse DIT: bit-reversed in -> natural out ----
  for (int lh = 0; lh <= 10; ++lh) {
    const int half = 1 << lh;
#pragma unroll 1
    for (int it = 0; it < 8; ++it) {
      int gg = it * 256 + tid;
      int c = gg >> 10;
      int bf = gg & 1023;
      int j = bf & (half - 1);
      int base = ((bf >> lh) << (lh + 1)) | j;
      float2 a = Z[c][base];
      float2 bw = cmulc(Z[c][base + half], tw[j << (10 - lh)]);
      Z[c][base] = make_float2(a.x + bw.x, a.y + bw.y);
      Z[c][base + half] = make_float2(a.x - bw.x, a.y - bw.y);
    }
    __syncthreads();
  }

  const float* xb = xin + (size_t)b * 2048 * 1024;
  float* ob = outp + (size_t)b * 2048 * 1024;
  const float inv = 1.0f / 2048.0f;
  for (int s = tid; s < 2048; s += 256) {
    float4 xv = *(const float4*)(xb + (size_t)s * 1024 + c0);
    float2 r0 = Z[0][s], r1 = Z[1][s];
    float4 o;
    o.x = xv.x * r0.x * inv;
    o.y = xv.y * r0.y * inv;
    o.z = xv.z * r1.x * inv;
    o.w = xv.w * r1.y * inv;
    *(float4*)(ob + (size_t)s * 1024 + c0) = o;
  }
}

// ======================= launch =======================
extern "C" void kernel_launch(void* const* d_in, const int* in_sizes, int n_in,
                              void* d_out, int out_size, void* d_ws, size_t ws_size,
                              hipStream_t stream) {
  const float* x    = (const float*)d_in[0];
  const float* wqkv = (const float*)d_in[1];
  const float* bqkv = (const float*)d_in[2];
  const float* wout = (const float*)d_in[3];
  const float* bout = (const float*)d_in[4];
  const float* w1   = (const float*)d_in[5];
  const float* b1   = (const float*)d_in[6];
  const float* w2   = (const float*)d_in[7];
  const float* b2   = (const float*)d_in[8];
  float* out = (float*)d_out;
  char* wsb = (char*)d_ws;
  const size_t MB = 1048576;

  f16*   xf    = (f16*)(wsb);
  f16*   wqf   = (f16*)(wsb + 16 * MB);
  f16*   wof   = (f16*)(wsb + 22 * MB);
  f16*   w1f   = (f16*)(wsb + 24 * MB);
  f16*   w2f   = (f16*)(wsb + 26 * MB);
  f16*   qkvF  = (f16*)(wsb + 28 * MB);
  f16*   VtF   = (f16*)(wsb + 76 * MB);
  f16*   attnF = (f16*)(wsb + 92 * MB);
  float* nico  = (float*)(wsb + 108 * MB);
  f16*   hF    = (f16*)(wsb + 140 * MB);
  float* chol  = (float*)(wsb + 156 * MB);

  conv_f16<<<4096, 256, 0, stream>>>(x, xf, 8388608);
  conv_f16<<<1536, 256, 0, stream>>>(wqkv, wqf, 3145728);
  conv_f16<<<512, 256, 0, stream>>>(wout, wof, 1048576);
  conv_f16<<<512, 256, 0, stream>>>(w1, w1f, 1048576);
  conv_f16<<<512, 256, 0, stream>>>(w2, w2f, 1048576);

  gemm_f16<0, 1><<<dim3(24, 64), 256, 0, stream>>>(xf, wqf, bqkv, qkvF, 3072, 1024, nullptr);
  vtrans<<<512, 256, 0, stream>>>(qkvF, VtF);
  flash_f16<<<512, 256, 0, stream>>>(qkvF, VtF, attnF);
  gemm_f16<0, 0><<<dim3(8, 64), 256, 0, stream>>>(attnF, wof, bout, nico, 1024, 1024, nullptr);
  gemm_f16<1, 1><<<dim3(8, 64), 256, 0, stream>>>(xf, w1f, b1, hF, 1024, 1024, nullptr);
  gemm_f16<2, 0><<<dim3(8, 64), 256, 0, stream>>>(hF, w2f, b2, chol, 1024, 1024, nico);
  spectral3<<<1024, 256, 0, stream>>>(chol, x, out);
}

// Round 7
// 434.251 us; speedup vs baseline: 1.4384x; 1.0974x over previous
//
#include <hip/hip_runtime.h>
#include <cstdint>

// B=4, S=2048, E=1024, H=4, DH=256, DQ=256
typedef _Float16 f16;
typedef unsigned short u16;
typedef __attribute__((ext_vector_type(8))) _Float16 half8;
typedef __attribute__((ext_vector_type(2))) __fp16 fp16x2;
typedef __attribute__((ext_vector_type(4))) float f32x4;

#define MFMA_F16(a, b, c) __builtin_amdgcn_mfma_f32_16x16x32_f16(a, b, c, 0, 0, 0)

// counted-vmcnt barrier primitives (T3/T4): never drain vmcnt to 0 in the main loop
#define WAITVM8() asm volatile("s_waitcnt vmcnt(8)" ::: "memory")
#define WAITVM0() asm volatile("s_waitcnt vmcnt(0)" ::: "memory")
#define BARRIER() do { asm volatile("" ::: "memory"); __builtin_amdgcn_s_barrier(); \
                       asm volatile("" ::: "memory"); } while (0)

__device__ inline void stage16(const void* g, void* l) {
#if defined(__has_builtin) && __has_builtin(__builtin_amdgcn_global_load_lds)
  __builtin_amdgcn_global_load_lds(
      (const __attribute__((address_space(1))) unsigned*)g,
      (__attribute__((address_space(3))) unsigned*)l, 16, 0, 0);
#else
  *(int4*)l = *(const int4*)g;
#endif
}

__device__ inline int pack_f16(float a, float b) {
#if defined(__has_builtin) && __has_builtin(__builtin_amdgcn_cvt_pkrtz)
  union { fp16x2 h; int i; } u;
  u.h = __builtin_amdgcn_cvt_pkrtz(a, b);
  return u.i;
#else
  union { f16 h[2]; int i; } u;
  u.h[0] = (f16)a; u.h[1] = (f16)b;
  return u.i;
#endif
}

// ======================= convert fp32 -> fp16 =======================
__global__ __launch_bounds__(256)
void conv_f16(const float* __restrict__ in, f16* __restrict__ out, int n) {
  int i = (blockIdx.x * 256 + threadIdx.x) * 8;
  if (i >= n) return;
  float4 a = *(const float4*)(in + i);
  float4 b = *(const float4*)(in + i + 4);
  half8 h;
  h[0] = (f16)a.x; h[1] = (f16)a.y; h[2] = (f16)a.z; h[3] = (f16)a.w;
  h[4] = (f16)b.x; h[5] = (f16)b.y; h[6] = (f16)b.z; h[7] = (f16)b.w;
  *(half8*)(out + i) = h;
}

// ======================= fp16 MFMA GEMM, counted-vmcnt 2-phase (unchanged) =======================
template<int EPI, int OUTF16>
__global__ __launch_bounds__(256, 2)
void gemm_f16(const f16* __restrict__ A, const f16* __restrict__ W,
              const float* __restrict__ bias, void* __restrict__ Cv,
              int N, int K, const float* __restrict__ aux) {
  __shared__ __align__(16) f16 lds[2][16384];
  const int tid = threadIdx.x;
  const int lane = tid & 63, w = tid >> 6;
  const int g = lane >> 4, lm = lane & 15;
  const int wr = w >> 1, wc = w & 1;
  const int m0 = blockIdx.y * 128, n0 = blockIdx.x * 128;

  const f16* src[8];
#pragma unroll
  for (int j = 0; j < 8; ++j) {
    int u = j * 256 + tid;
    if (u < 1024) {
      int row = u >> 3, s = u & 7;
      src[j] = A + (size_t)(m0 + row) * K + ((s ^ (row & 7)) << 3);
    } else {
      int v = u - 1024;
      int row = v >> 3, s = v & 7;
      src[j] = W + (size_t)(n0 + row) * K + ((s ^ (row & 7)) << 3);
    }
  }

  f32x4 acc[4][4];
#pragma unroll
  for (int mt = 0; mt < 4; ++mt)
#pragma unroll
    for (int nt = 0; nt < 4; ++nt) acc[mt][nt] = (f32x4){0.f, 0.f, 0.f, 0.f};

#pragma unroll
  for (int j = 0; j < 8; ++j) stage16(src[j], &lds[0][(j * 256 + tid) * 8]);
  __syncthreads();

  const int KT = K >> 6;
#pragma unroll 1
  for (int t = 0; t < KT; ++t) {
    const f16* bufA = lds[t & 1];
    const f16* bufB = bufA + 8192;
    if (t + 1 < KT) {
#pragma unroll
      for (int j = 0; j < 8; ++j) {
        src[j] += 64;
        stage16(src[j], &lds[(t + 1) & 1][(j * 256 + tid) * 8]);
      }
      WAITVM8();
    } else {
      WAITVM0();
    }
    BARRIER();
#pragma unroll
    for (int ks = 0; ks < 2; ++ks) {
      half8 a[4], b[4];
#pragma unroll
      for (int mt = 0; mt < 4; ++mt) {
        int row = wr * 64 + mt * 16 + lm;
        a[mt] = *(const half8*)(bufA + row * 64 + (((ks * 4 + g) ^ (row & 7)) << 3));
      }
#pragma unroll
      for (int nt = 0; nt < 4; ++nt) {
        int row = wc * 64 + nt * 16 + lm;
        b[nt] = *(const half8*)(bufB + row * 64 + (((ks * 4 + g) ^ (row & 7)) << 3));
      }
#pragma unroll
      for (int mt = 0; mt < 4; ++mt)
#pragma unroll
        for (int nt = 0; nt < 4; ++nt)
          acc[mt][nt] = MFMA_F16(a[mt], b[nt], acc[mt][nt]);
    }
    BARRIER();
  }

  const int crow = m0 + wr * 64 + g * 4;
  const int ccol = n0 + wc * 64 + lm;
#pragma unroll
  for (int nt = 0; nt < 4; ++nt) {
    float bb = bias[ccol + nt * 16];
#pragma unroll
    for (int mt = 0; mt < 4; ++mt) {
#pragma unroll
      for (int r = 0; r < 4; ++r) {
        size_t idx = (size_t)(crow + mt * 16 + r) * N + ccol + nt * 16;
        float v = acc[mt][nt][r] + bb;
        if (EPI == 1) v = 0.5f * v * (1.0f + erff(v * 0.70710678118654752f));
        if (EPI == 2) v = (0.9f * aux[idx] + 0.1f * v) * 2.0f;
        if (OUTF16) ((f16*)Cv)[idx] = (f16)v;
        else        ((float*)Cv)[idx] = v;
      }
    }
  }
}

// ======================= V transpose (unchanged) =======================
__global__ __launch_bounds__(256)
void vtrans(const f16* __restrict__ qkv, f16* __restrict__ Vt) {
  __shared__ unsigned vlds[64][65];
  const int tid = threadIdx.x;
  const int bh = blockIdx.x >> 5, st = blockIdx.x & 31;
  const int b = bh >> 2, h = bh & 3;
  const int s0 = st * 64;
  const u16* q16 = (const u16*)qkv;
  u16* v16 = (u16*)Vt;
#pragma unroll 1
  for (int dc = 0; dc < 4; ++dc) {
    __syncthreads();
#pragma unroll 1
    for (int i = 0; i < 16; ++i) {
      int idx = i * 256 + tid;
      int s = idx >> 6, dl = idx & 63;
      vlds[dl][s] = q16[(size_t)(b * 2048 + s0 + s) * 3072 + 2048 + h * 256 + dc * 64 + dl];
    }
    __syncthreads();
#pragma unroll 1
    for (int i = 0; i < 16; ++i) {
      int idx = i * 256 + tid;
      int dl = idx >> 6, s = idx & 63;
      v16[((size_t)bh * 256 + dc * 64 + dl) * 2048 + s0 + s] = (u16)vlds[dl][s];
    }
  }
}

// ======================= fp16 flash attention v4: swapped QK^T, in-register P =======================
// 4 waves x 16 q (BQ=64), TKV=32. K,V double-buffered via global_load_lds, counted vmcnt.
// S^T = mfma(K,Q): lane holds P[q=lm][8 kv] -> softmax = 2 shuffles; P->A-frag via
// cvt_pkrtz + 8 shuffles (register-only, no LDS bounce). LDS 64 KB (2 blocks/CU).
__global__ __launch_bounds__(256, 2)
void flash_f16(const f16* __restrict__ qkv, const f16* __restrict__ Vt,
               f16* __restrict__ attn) {
  __shared__ __align__(16) f16 lds[32768];   // K[2][32][256] @0, V[2][256][32] @16384
  const int tid = threadIdx.x;
  const int lane = tid & 63, w = tid >> 6;
  const int g = lane >> 4, lm = lane & 15;
  const int raw = blockIdx.x;
  const int bh = (raw & 7) * 2 + (raw >> 8);   // XCD-clustered (b,h)
  const int qt = (raw >> 3) & 31;
  const int b = bh >> 2, h = bh & 3;
  const int q0 = qt * 64 + w * 16;
  const float SC = 0.09016844005555896f;       // log2(e)/16

  half8 qf[8];   // Q rows q0+lm (B-operand of swapped QK^T)
  {
    const f16* qp = qkv + (size_t)(b * 2048 + q0 + lm) * 3072 + h * 256 + g * 8;
#pragma unroll
    for (int c = 0; c < 8; ++c) qf[c] = *(const half8*)(qp + c * 32);
  }

  const f16* kbase = qkv + (size_t)b * 2048 * 3072 + 1024 + h * 256;
  const f16* vbase = Vt + (size_t)bh * 256 * 2048;
  int kofs[4], vofs[4];
#pragma unroll
  for (int j = 0; j < 4; ++j) {
    int u = j * 256 + tid;
    int kv = u >> 5, s = u & 31;
    kofs[j] = kv * 3072 + ((s ^ (kv & 7)) << 3);
    int d = u >> 2, sl = u & 3;
    vofs[j] = d * 2048 + ((sl ^ ((d >> 1) & 3)) << 3);
  }

  f32x4 o[16];
#pragma unroll
  for (int f = 0; f < 16; ++f) o[f] = (f32x4){0.f, 0.f, 0.f, 0.f};
  float m = -3e38f, l = 0.f;   // per q-row q = lm (replicated across g)

  // prologue: tile 0 -> buf0
#pragma unroll
  for (int j = 0; j < 4; ++j) {
    stage16(kbase + kofs[j], &lds[(j * 256 + tid) * 8]);
    stage16(vbase + vofs[j], &lds[16384 + (j * 256 + tid) * 8]);
  }
  __syncthreads();   // one-time full drain (also covers qf)

#pragma unroll 1
  for (int t = 0; t < 64; ++t) {
    const int cb_ = t & 1;
    if (t < 63) {
      const int nb = cb_ ^ 1;
      const int kt = (t + 1) * 98304, vt_ = (t + 1) * 32;
#pragma unroll
      for (int j = 0; j < 4; ++j) {
        stage16(kbase + kofs[j] + kt, &lds[nb * 8192 + (j * 256 + tid) * 8]);
        stage16(vbase + vofs[j] + vt_, &lds[16384 + nb * 8192 + (j * 256 + tid) * 8]);
      }
      WAITVM8();   // tile-t landed; tile-(t+1)'s 8 loads stay in flight
    } else {
      WAITVM0();
    }
    BARRIER();

    const f16* kb = &lds[cb_ * 8192];
    const f16* vb = &lds[16384 + cb_ * 8192];

    // ---- swapped QK^T: S^T[kv][q] = mfma(A=K, B=Q) ----
    f32x4 s0 = {0.f, 0.f, 0.f, 0.f}, s1 = {0.f, 0.f, 0.f, 0.f};
    __builtin_amdgcn_s_setprio(1);
#pragma unroll
    for (int c = 0; c < 8; ++c) {
      int slot = ((c * 4 + g) ^ (lm & 7)) << 3;
      half8 b0 = *(const half8*)(kb + lm * 256 + slot);          // K rows 0..15
      half8 b1 = *(const half8*)(kb + (16 + lm) * 256 + slot);   // K rows 16..31
      s0 = MFMA_F16(b0, qf[c], s0);
      s1 = MFMA_F16(b1, qf[c], s1);
    }
    __builtin_amdgcn_s_setprio(0);

    // lane (g,lm): s0[r] = S[q=lm][kv=4g+r], s1[r] = S[q=lm][kv=16+4g+r]
    float a0[4], a1[4];
#pragma unroll
    for (int r = 0; r < 4; ++r) { a0[r] = s0[r] * SC; a1[r] = s1[r] * SC; }

    // row-max over all 32 kv for q=lm: 7 local + 2 shuffles
    float mx = fmaxf(fmaxf(fmaxf(a0[0], a0[1]), fmaxf(a0[2], a0[3])),
                     fmaxf(fmaxf(a1[0], a1[1]), fmaxf(a1[2], a1[3])));
    mx = fmaxf(mx, __shfl_xor(mx, 16));
    mx = fmaxf(mx, __shfl_xor(mx, 32));

    // defer-max: rescale only when max grew by > 8 (log2 domain, P bounded by 2^8)
    if (!__all(mx <= m + 8.0f)) {
      float mn = fmaxf(m, mx);
      float corr = exp2f(m - mn);
      m = mn; l *= corr;
#pragma unroll
      for (int r = 0; r < 4; ++r) {
        float cr = __shfl(corr, ((lane >> 2) & 12) + r);   // corr for q = 4g+r
#pragma unroll
        for (int f = 0; f < 16; ++f) o[f][r] *= cr;
      }
    }

    // P = exp2(S - m), row-sum: 7 local adds + 2 shuffles
    float e0[4], e1[4], rs;
#pragma unroll
    for (int r = 0; r < 4; ++r) { e0[r] = exp2f(a0[r] - m); e1[r] = exp2f(a1[r] - m); }
    rs = ((e0[0] + e0[1]) + (e0[2] + e0[3])) + ((e1[0] + e1[1]) + (e1[2] + e1[3]));
    rs += __shfl_xor(rs, 16);
    rs += __shfl_xor(rs, 32);
    l += rs;

    // ---- P -> A-fragment, register-only redistribution ----
    // target lane (g,lm) needs P[q=lm][kv=8g..8g+7]; sources at lane 32(g&1)+lm (+16)
    int A01 = pack_f16(e0[0], e0[1]);   // kv (4g, 4g+1)
    int A23 = pack_f16(e0[2], e0[3]);   // kv (4g+2, 4g+3)
    int B01 = pack_f16(e1[0], e1[1]);   // kv (16+4g, 16+4g+1)
    int B23 = pack_f16(e1[2], e1[3]);   // kv (16+4g+2, 16+4g+3)
    const int s1l = ((lane & 16) << 1) + lm;
    const int s2l = s1l + 16;
    int t0a = __shfl(A01, s1l), t0b = __shfl(B01, s1l);
    int t1a = __shfl(A23, s1l), t1b = __shfl(B23, s1l);
    int t2a = __shfl(A01, s2l), t2b = __shfl(B01, s2l);
    int t3a = __shfl(A23, s2l), t3b = __shfl(B23, s2l);
    union { int i[4]; half8 h; } pau;
    const bool hi = lane >= 32;   // g >= 2 -> take s1 (kv>=16) packs
    pau.i[0] = hi ? t0b : t0a;
    pau.i[1] = hi ? t1b : t1a;
    pau.i[2] = hi ? t2b : t2a;
    pau.i[3] = hi ? t3b : t3a;
    half8 pa = pau.h;

    // ---- PV: O[q][d] += P V ----
    __builtin_amdgcn_s_setprio(1);
#pragma unroll
    for (int f = 0; f < 16; ++f) {
      int d = f * 16 + lm;
      half8 bv = *(const half8*)(vb + d * 32 + ((g ^ ((d >> 1) & 3)) << 3));
      o[f] = MFMA_F16(pa, bv, o[f]);
    }
    __builtin_amdgcn_s_setprio(0);

    BARRIER();   // all waves done reading buf[t&1]; no vmcnt drain
  }

  // epilogue: O row q = 4g+r needs l[q] from lane lm=4g+r
  float inv[4];
#pragma unroll
  for (int r = 0; r < 4; ++r) inv[r] = 1.0f / __shfl(l, ((lane >> 2) & 12) + r);
#pragma unroll
  for (int f = 0; f < 16; ++f)
#pragma unroll
    for (int r = 0; r < 4; ++r)
      attn[(size_t)(b * 2048 + q0 + g * 4 + r) * 1024 + h * 256 + f * 16 + lm] =
          (f16)(o[f][r] * inv[r]);
}

// ======================= Spectral v3 (unchanged) =======================
__device__ inline float2 cmul(float2 a, float2 b) {
  return make_float2(a.x * b.x - a.y * b.y, a.x * b.y + a.y * b.x);
}
__device__ inline float2 cmulc(float2 a, float2 b) {
  return make_float2(a.x * b.x + a.y * b.y, a.y * b.x - a.x * b.y);
}
__device__ inline void qcube(float2& w, float2& x, float2& y, float2& z, float2 f) {
  w = cmul(w, f); x = cmul(x, f); y = cmul(y, f); z = cmul(z, f);
  float2 a2 = cmul(w, w);
  float2 sx = cmul(x, x), sy = cmul(y, y), sz = cmul(z, z);
  float2 s = make_float2(sx.x + sy.x + sz.x, sx.y + sy.y + sz.y);
  float2 t3 = make_float2(a2.x - 3.f * s.x, a2.y - 3.f * s.y);
  float2 cf = make_float2(3.f * a2.x - s.x, 3.f * a2.y - s.y);
  w = cmul(w, t3); x = cmul(cf, x); y = cmul(cf, y); z = cmul(cf, z);
}

__global__ __launch_bounds__(256)
void spectral3(const float* __restrict__ chol, const float* __restrict__ xin,
               float* __restrict__ outp) {
  __shared__ __align__(16) float2 Z[2][2048];
  __shared__ float2 tw[1024];
  const int tid = threadIdx.x;
  const int b = blockIdx.x >> 8;
  const int qd = blockIdx.x & 255;
  const size_t c0 = (size_t)qd * 4;
  const float* cb = chol + (size_t)b * 2048 * 1024;

  for (int j = tid; j < 1024; j += 256) {
    float ang = -6.2831853071795864769f * (float)j * (1.0f / 2048.0f);
    float sv, cv; sincosf(ang, &sv, &cv);
    tw[j] = make_float2(cv, sv);
  }
  for (int s = tid; s < 2048; s += 256) {
    float4 v = *(const float4*)(cb + (size_t)s * 1024 + c0);
    Z[0][s] = make_float2(v.x, v.y);
    Z[1][s] = make_float2(v.z, v.w);
  }
  __syncthreads();

  for (int lh = 10; lh >= 0; --lh) {
    const int half = 1 << lh;
#pragma unroll 1
    for (int it = 0; it < 8; ++it) {
      int gg = it * 256 + tid;
      int c = gg >> 10;
      int bf = gg & 1023;
      int j = bf & (half - 1);
      int base = ((bf >> lh) << (lh + 1)) | j;
      float2 a = Z[c][base];
      float2 bb = Z[c][base + half];
      float2 dif = make_float2(a.x - bb.x, a.y - bb.y);
      Z[c][base] = make_float2(a.x + bb.x, a.y + bb.y);
      Z[c][base + half] = cmul(dif, tw[j << (10 - lh)]);
    }
    __syncthreads();
  }

#pragma unroll 1
  for (int it = 0; it < 4; ++it) {
    int jj = it * 256 + tid;
    int nrep = (jj == 0) ? 2 : 1;
#pragma unroll 1
    for (int rep = 0; rep < nrep; ++rep) {
      int k  = (jj == 0) ? (rep ? 1024 : 0) : jj;
      int kn = (jj == 0) ? k : 2048 - jj;
      int p  = __brev((unsigned)k) >> 21;
      int pp = __brev((unsigned)kn) >> 21;
      float2 z0p = Z[0][p], z0q = Z[0][pp];
      float2 z1p = Z[1][p], z1q = Z[1][pp];
      float2 wk = make_float2(0.5f * (z0p.x + z0q.x), 0.5f * (z0p.y - z0q.y));
      float2 xk = make_float2(0.5f * (z0p.y + z0q.y), 0.5f * (z0q.x - z0p.x));
      float2 yk = make_float2(0.5f * (z1p.x + z1q.x), 0.5f * (z1p.y - z1q.y));
      float2 zk = make_float2(0.5f * (z1p.y + z1q.y), 0.5f * (z1q.x - z1p.x));
      float2 wn = make_float2(0.5f * (z0q.x + z0p.x), 0.5f * (z0q.y - z0p.y));
      float2 xn = make_float2(0.5f * (z0q.y + z0p.y), 0.5f * (z0p.x - z0q.x));
      float2 yn = make_float2(0.5f * (z1q.x + z1p.x), 0.5f * (z1q.y - z1p.y));
      float2 zn = make_float2(0.5f * (z1q.y + z1p.y), 0.5f * (z1p.x - z1q.x));
      float sk, ck, sn, cn;
      sincosf(1.5f * atanf(logf((float)k + 1e-10f)), &sk, &ck);
      sincosf(1.5f * atanf(logf((float)kn + 1e-10f)), &sn, &cn);
      qcube(wk, xk, yk, zk, make_float2(ck, sk));
      qcube(wn, xn, yn, zn, make_float2(cn, sn));
      Z[0][p]  = make_float2(0.5f * (wk.x + wn.x) - 0.5f * (xk.y - xn.y),
                             0.5f * (wk.y - wn.y) + 0.5f * (xk.x + xn.x));
      Z[0][pp] = make_float2(0.5f * (wn.x + wk.x) - 0.5f * (xn.y - xk.y),
                             0.5f * (wn.y - wk.y) + 0.5f * (xn.x + xk.x));
      Z[1][p]  = make_float2(0.5f * (yk.x + yn.x) - 0.5f * (zk.y - zn.y),
                             0.5f * (yk.y - yn.y) + 0.5f * (zk.x + zn.x));
      Z[1][pp] = make_float2(0.5f * (yn.x + yk.x) - 0.5f * (zn.y - zk.y),
                             0.5f * (yn.y - yk.y) + 0.5f * (zn.x + zk.x));
    }
  }
  __syncthreads();

  for (int lh = 0; lh <= 10; ++lh) {
    const int half = 1 << lh;
#pragma unroll 1
    for (int it = 0; it < 8; ++it) {
      int gg = it * 256 + tid;
      int c = gg >> 10;
      int bf = gg & 1023;
      int j = bf & (half - 1);
      int base = ((bf >> lh) << (lh + 1)) | j;
      float2 a = Z[c][base];
      float2 bw = cmulc(Z[c][base + half], tw[j << (10 - lh)]);
      Z[c][base] = make_float2(a.x + bw.x, a.y + bw.y);
      Z[c][base + half] = make_float2(a.x - bw.x, a.y - bw.y);
    }
    __syncthreads();
  }

  const float* xb = xin + (size_t)b * 2048 * 1024;
  float* ob = outp + (size_t)b * 2048 * 1024;
  const float inv = 1.0f / 2048.0f;
  for (int s = tid; s < 2048; s += 256) {
    float4 xv = *(const float4*)(xb + (size_t)s * 1024 + c0);
    float2 r0 = Z[0][s], r1 = Z[1][s];
    float4 o;
    o.x = xv.x * r0.x * inv;
    o.y = xv.y * r0.y * inv;
    o.z = xv.z * r1.x * inv;
    o.w = xv.w * r1.y * inv;
    *(float4*)(ob + (size_t)s * 1024 + c0) = o;
  }
}

// ======================= launch =======================
extern "C" void kernel_launch(void* const* d_in, const int* in_sizes, int n_in,
                              void* d_out, int out_size, void* d_ws, size_t ws_size,
                              hipStream_t stream) {
  const float* x    = (const float*)d_in[0];
  const float* wqkv = (const float*)d_in[1];
  const float* bqkv = (const float*)d_in[2];
  const float* wout = (const float*)d_in[3];
  const float* bout = (const float*)d_in[4];
  const float* w1   = (const float*)d_in[5];
  const float* b1   = (const float*)d_in[6];
  const float* w2   = (const float*)d_in[7];
  const float* b2   = (const float*)d_in[8];
  float* out = (float*)d_out;
  char* wsb = (char*)d_ws;
  const size_t MB = 1048576;

  f16*   xf    = (f16*)(wsb);
  f16*   wqf   = (f16*)(wsb + 16 * MB);
  f16*   wof   = (f16*)(wsb + 22 * MB);
  f16*   w1f   = (f16*)(wsb + 24 * MB);
  f16*   w2f   = (f16*)(wsb + 26 * MB);
  f16*   qkvF  = (f16*)(wsb + 28 * MB);
  f16*   VtF   = (f16*)(wsb + 76 * MB);
  f16*   attnF = (f16*)(wsb + 92 * MB);
  float* nico  = (float*)(wsb + 108 * MB);
  f16*   hF    = (f16*)(wsb + 140 * MB);
  float* chol  = (float*)(wsb + 156 * MB);

  conv_f16<<<4096, 256, 0, stream>>>(x, xf, 8388608);
  conv_f16<<<1536, 256, 0, stream>>>(wqkv, wqf, 3145728);
  conv_f16<<<512, 256, 0, stream>>>(wout, wof, 1048576);
  conv_f16<<<512, 256, 0, stream>>>(w1, w1f, 1048576);
  conv_f16<<<512, 256, 0, stream>>>(w2, w2f, 1048576);

  gemm_f16<0, 1><<<dim3(24, 64), 256, 0, stream>>>(xf, wqf, bqkv, qkvF, 3072, 1024, nullptr);
  vtrans<<<512, 256, 0, stream>>>(qkvF, VtF);
  flash_f16<<<512, 256, 0, stream>>>(qkvF, VtF, attnF);
  gemm_f16<0, 0><<<dim3(8, 64), 256, 0, stream>>>(attnF, wof, bout, nico, 1024, 1024, nullptr);
  gemm_f16<1, 1><<<dim3(8, 64), 256, 0, stream>>>(xf, w1f, b1, hF, 1024, 1024, nullptr);
  gemm_f16<2, 0><<<dim3(8, 64), 256, 0, stream>>>(hF, w2f, b2, chol, 1024, 1024, nico);
  spectral3<<<1024, 256, 0, stream>>>(chol, x, out);
}

// Round 8
// 416.656 us; speedup vs baseline: 1.4991x; 1.0422x over previous
//
#include <hip/hip_runtime.h>
#include <cstdint>

// B=4, S=2048, E=1024, H=4, DH=256, DQ=256
typedef _Float16 f16;
typedef unsigned short u16;
typedef __attribute__((ext_vector_type(8))) _Float16 half8;
typedef __attribute__((ext_vector_type(2))) __fp16 fp16x2;
typedef __attribute__((ext_vector_type(4))) float f32x4;

#define MFMA_F16(a, b, c) __builtin_amdgcn_mfma_f32_16x16x32_f16(a, b, c, 0, 0, 0)

// counted-vmcnt barrier primitives (T3/T4)
#define WAITVM8() asm volatile("s_waitcnt vmcnt(8)" ::: "memory")
#define WAITVM4() asm volatile("s_waitcnt vmcnt(4)" ::: "memory")
#define WAITVM0() asm volatile("s_waitcnt vmcnt(0)" ::: "memory")
#define BARRIER() do { asm volatile("" ::: "memory"); __builtin_amdgcn_s_barrier(); \
                       asm volatile("" ::: "memory"); } while (0)

__device__ inline void stage16(const void* g, void* l) {
#if defined(__has_builtin) && __has_builtin(__builtin_amdgcn_global_load_lds)
  __builtin_amdgcn_global_load_lds(
      (const __attribute__((address_space(1))) unsigned*)g,
      (__attribute__((address_space(3))) unsigned*)l, 16, 0, 0);
#else
  *(int4*)l = *(const int4*)g;
#endif
}

__device__ inline int pack_f16(float a, float b) {
#if defined(__has_builtin) && __has_builtin(__builtin_amdgcn_cvt_pkrtz)
  union { fp16x2 h; int i; } u;
  u.h = __builtin_amdgcn_cvt_pkrtz(a, b);
  return u.i;
#else
  union { f16 h[2]; int i; } u;
  u.h[0] = (f16)a; u.h[1] = (f16)b;
  return u.i;
#endif
}

// ======================= fused fp32 -> fp16 conversion (x | wqkv | wout | w1 | w2) =======================
// dst regions are contiguous in ws: xf@0(8388608), wqf(3145728), wof(1048576), w1f(1048576), w2f(1048576)
__global__ __launch_bounds__(256)
void conv_all(const float* __restrict__ x, const float* __restrict__ wqkv,
              const float* __restrict__ wout, const float* __restrict__ w1,
              const float* __restrict__ w2, f16* __restrict__ dst) {
  int i = (blockIdx.x * 256 + threadIdx.x) * 8;
  const float* src; int off;
  if (i < 8388608)       { src = x;    off = i; }
  else if (i < 11534336) { src = wqkv; off = i - 8388608; }
  else if (i < 12582912) { src = wout; off = i - 11534336; }
  else if (i < 13631488) { src = w1;   off = i - 12582912; }
  else                   { src = w2;   off = i - 13631488; }
  float4 a = *(const float4*)(src + off);
  float4 b = *(const float4*)(src + off + 4);
  half8 h;
  h[0] = (f16)a.x; h[1] = (f16)a.y; h[2] = (f16)a.z; h[3] = (f16)a.w;
  h[4] = (f16)b.x; h[5] = (f16)b.y; h[6] = (f16)b.z; h[7] = (f16)b.w;
  *(half8*)(dst + i) = h;
}

// ======================= fp16 MFMA GEMM, counted-vmcnt 2-phase (unchanged) =======================
template<int EPI, int OUTF16>
__global__ __launch_bounds__(256, 2)
void gemm_f16(const f16* __restrict__ A, const f16* __restrict__ W,
              const float* __restrict__ bias, void* __restrict__ Cv,
              int N, int K, const float* __restrict__ aux) {
  __shared__ __align__(16) f16 lds[2][16384];
  const int tid = threadIdx.x;
  const int lane = tid & 63, w = tid >> 6;
  const int g = lane >> 4, lm = lane & 15;
  const int wr = w >> 1, wc = w & 1;
  const int m0 = blockIdx.y * 128, n0 = blockIdx.x * 128;

  const f16* src[8];
#pragma unroll
  for (int j = 0; j < 8; ++j) {
    int u = j * 256 + tid;
    if (u < 1024) {
      int row = u >> 3, s = u & 7;
      src[j] = A + (size_t)(m0 + row) * K + ((s ^ (row & 7)) << 3);
    } else {
      int v = u - 1024;
      int row = v >> 3, s = v & 7;
      src[j] = W + (size_t)(n0 + row) * K + ((s ^ (row & 7)) << 3);
    }
  }

  f32x4 acc[4][4];
#pragma unroll
  for (int mt = 0; mt < 4; ++mt)
#pragma unroll
    for (int nt = 0; nt < 4; ++nt) acc[mt][nt] = (f32x4){0.f, 0.f, 0.f, 0.f};

#pragma unroll
  for (int j = 0; j < 8; ++j) stage16(src[j], &lds[0][(j * 256 + tid) * 8]);
  __syncthreads();

  const int KT = K >> 6;
#pragma unroll 1
  for (int t = 0; t < KT; ++t) {
    const f16* bufA = lds[t & 1];
    const f16* bufB = bufA + 8192;
    if (t + 1 < KT) {
#pragma unroll
      for (int j = 0; j < 8; ++j) {
        src[j] += 64;
        stage16(src[j], &lds[(t + 1) & 1][(j * 256 + tid) * 8]);
      }
      WAITVM8();
    } else {
      WAITVM0();
    }
    BARRIER();
#pragma unroll
    for (int ks = 0; ks < 2; ++ks) {
      half8 a[4], b[4];
#pragma unroll
      for (int mt = 0; mt < 4; ++mt) {
        int row = wr * 64 + mt * 16 + lm;
        a[mt] = *(const half8*)(bufA + row * 64 + (((ks * 4 + g) ^ (row & 7)) << 3));
      }
#pragma unroll
      for (int nt = 0; nt < 4; ++nt) {
        int row = wc * 64 + nt * 16 + lm;
        b[nt] = *(const half8*)(bufB + row * 64 + (((ks * 4 + g) ^ (row & 7)) << 3));
      }
#pragma unroll
      for (int mt = 0; mt < 4; ++mt)
#pragma unroll
        for (int nt = 0; nt < 4; ++nt)
          acc[mt][nt] = MFMA_F16(a[mt], b[nt], acc[mt][nt]);
    }
    BARRIER();
  }

  const int crow = m0 + wr * 64 + g * 4;
  const int ccol = n0 + wc * 64 + lm;
#pragma unroll
  for (int nt = 0; nt < 4; ++nt) {
    float bb = bias[ccol + nt * 16];
#pragma unroll
    for (int mt = 0; mt < 4; ++mt) {
#pragma unroll
      for (int r = 0; r < 4; ++r) {
        size_t idx = (size_t)(crow + mt * 16 + r) * N + ccol + nt * 16;
        float v = acc[mt][nt][r] + bb;
        if (EPI == 1) v = 0.5f * v * (1.0f + erff(v * 0.70710678118654752f));
        if (EPI == 2) v = (0.9f * aux[idx] + 0.1f * v) * 2.0f;
        if (OUTF16) ((f16*)Cv)[idx] = (f16)v;
        else        ((float*)Cv)[idx] = v;
      }
    }
  }
}

// ======================= V transpose (unchanged) =======================
__global__ __launch_bounds__(256)
void vtrans(const f16* __restrict__ qkv, f16* __restrict__ Vt) {
  __shared__ unsigned vlds[64][65];
  const int tid = threadIdx.x;
  const int bh = blockIdx.x >> 5, st = blockIdx.x & 31;
  const int b = bh >> 2, h = bh & 3;
  const int s0 = st * 64;
  const u16* q16 = (const u16*)qkv;
  u16* v16 = (u16*)Vt;
#pragma unroll 1
  for (int dc = 0; dc < 4; ++dc) {
    __syncthreads();
#pragma unroll 1
    for (int i = 0; i < 16; ++i) {
      int idx = i * 256 + tid;
      int s = idx >> 6, dl = idx & 63;
      vlds[dl][s] = q16[(size_t)(b * 2048 + s0 + s) * 3072 + 2048 + h * 256 + dc * 64 + dl];
    }
    __syncthreads();
#pragma unroll 1
    for (int i = 0; i < 16; ++i) {
      int idx = i * 256 + tid;
      int dl = idx >> 6, s = idx & 63;
      v16[((size_t)bh * 256 + dc * 64 + dl) * 2048 + s0 + s] = (u16)vlds[dl][s];
    }
  }
}

// ======================= fp16 flash attention v5: deferred-PV pipeline =======================
// 4 waves x 16 q (BQ=64), TKV=32. At iter t: stage K(t+1),V(t); QK(t); PV(t-1) (MFMA)
// overlapped with softmax(t) (VALU); P carried in registers. Counted vmcnt, 2 barriers/iter.
__global__ __launch_bounds__(256, 2)
void flash_f16(const f16* __restrict__ qkv, const f16* __restrict__ Vt,
               f16* __restrict__ attn) {
  __shared__ __align__(16) f16 lds[32768];   // K[2][32][256] @0, V[2][256][32] @16384
  const int tid = threadIdx.x;
  const int lane = tid & 63, w = tid >> 6;
  const int g = lane >> 4, lm = lane & 15;
  const int raw = blockIdx.x;
  const int bh = (raw & 7) * 2 + (raw >> 8);   // XCD-clustered (b,h)
  const int qt = (raw >> 3) & 31;
  const int b = bh >> 2, h = bh & 3;
  const int q0 = qt * 64 + w * 16;
  const float SC = 0.09016844005555896f;       // log2(e)/16

  half8 qf[8];   // Q rows q0+lm (B-operand of swapped QK^T)
  {
    const f16* qp = qkv + (size_t)(b * 2048 + q0 + lm) * 3072 + h * 256 + g * 8;
#pragma unroll
    for (int c = 0; c < 8; ++c) qf[c] = *(const half8*)(qp + c * 32);
  }

  const f16* kbase = qkv + (size_t)b * 2048 * 3072 + 1024 + h * 256;
  const f16* vbase = Vt + (size_t)bh * 256 * 2048;
  int kofs[4], vofs[4];
#pragma unroll
  for (int j = 0; j < 4; ++j) {
    int u = j * 256 + tid;
    int kv = u >> 5, s = u & 31;
    kofs[j] = kv * 3072 + ((s ^ (kv & 7)) << 3);
    int d = u >> 2, sl = u & 3;
    vofs[j] = d * 2048 + ((sl ^ ((d >> 1) & 3)) << 3);
  }

  f32x4 o[16];
#pragma unroll
  for (int f = 0; f < 16; ++f) o[f] = (f32x4){0.f, 0.f, 0.f, 0.f};
  float m = -3e38f, l = 0.f;   // per q-row q = lm (replicated across g)
  half8 paP = (half8){0, 0, 0, 0, 0, 0, 0, 0};   // P(t-1) A-fragment

  // prologue: K(0) -> kbuf0 (V(0) staged inside iter 0)
#pragma unroll
  for (int j = 0; j < 4; ++j) stage16(kbase + kofs[j], &lds[(j * 256 + tid) * 8]);

#pragma unroll 1
  for (int t = 0; t < 64; ++t) {
    const int cb_ = t & 1;
    // stage K(t+1) into kbuf[t+1 & 1], V(t) into vbuf[t & 1]
    if (t < 63) {
      const int kt = (t + 1) * 98304;
#pragma unroll
      for (int j = 0; j < 4; ++j)
        stage16(kbase + kofs[j] + kt, &lds[(cb_ ^ 1) * 8192 + (j * 256 + tid) * 8]);
    }
    {
      const int vt_ = t * 32;
#pragma unroll
      for (int j = 0; j < 4; ++j)
        stage16(vbase + vofs[j] + vt_, &lds[16384 + cb_ * 8192 + (j * 256 + tid) * 8]);
    }
    if (t < 63) { WAITVM8(); } else { WAITVM4(); }   // K(t),V(t-1) landed; newest stay in flight
    BARRIER();

    const f16* kb = &lds[cb_ * 8192];

    // ---- QK(t): S^T[kv][q] = mfma(A=K, B=Q) ----
    f32x4 s0 = {0.f, 0.f, 0.f, 0.f}, s1 = {0.f, 0.f, 0.f, 0.f};
    __builtin_amdgcn_s_setprio(1);
#pragma unroll
    for (int c = 0; c < 8; ++c) {
      int slot = ((c * 4 + g) ^ (lm & 7)) << 3;
      half8 b0 = *(const half8*)(kb + lm * 256 + slot);
      half8 b1 = *(const half8*)(kb + (16 + lm) * 256 + slot);
      s0 = MFMA_F16(b0, qf[c], s0);
      s1 = MFMA_F16(b1, qf[c], s1);
    }
    __builtin_amdgcn_s_setprio(0);

    // ---- PV(t-1): independent of softmax(t) -> overlaps its VALU ----
    if (t > 0) {
      const f16* vbp = &lds[16384 + (cb_ ^ 1) * 8192];
      __builtin_amdgcn_s_setprio(1);
#pragma unroll
      for (int f = 0; f < 16; ++f) {
        int d = f * 16 + lm;
        half8 bv = *(const half8*)(vbp + d * 32 + ((g ^ ((d >> 1) & 3)) << 3));
        o[f] = MFMA_F16(paP, bv, o[f]);
      }
      __builtin_amdgcn_s_setprio(0);
    }

    // ---- softmax(t) (log2 domain, defer-max); O-rescale after PV(t-1) ----
    float a0[4], a1[4];
#pragma unroll
    for (int r = 0; r < 4; ++r) { a0[r] = s0[r] * SC; a1[r] = s1[r] * SC; }
    float mx = fmaxf(fmaxf(fmaxf(a0[0], a0[1]), fmaxf(a0[2], a0[3])),
                     fmaxf(fmaxf(a1[0], a1[1]), fmaxf(a1[2], a1[3])));
    mx = fmaxf(mx, __shfl_xor(mx, 16));
    mx = fmaxf(mx, __shfl_xor(mx, 32));

    if (!__all(mx <= m + 8.0f)) {
      float mn = fmaxf(m, mx);
      float corr = exp2f(m - mn);
      m = mn; l *= corr;
#pragma unroll
      for (int r = 0; r < 4; ++r) {
        float cr = __shfl(corr, ((lane >> 2) & 12) + r);   // corr for q = 4g+r
#pragma unroll
        for (int f = 0; f < 16; ++f) o[f][r] *= cr;
      }
    }

    float e0[4], e1[4], rs;
#pragma unroll
    for (int r = 0; r < 4; ++r) { e0[r] = exp2f(a0[r] - m); e1[r] = exp2f(a1[r] - m); }
    rs = ((e0[0] + e0[1]) + (e0[2] + e0[3])) + ((e1[0] + e1[1]) + (e1[2] + e1[3]));
    rs += __shfl_xor(rs, 16);
    rs += __shfl_xor(rs, 32);
    l += rs;

    // ---- P(t) -> A-fragment (register-only), saved for next iteration ----
    int A01 = pack_f16(e0[0], e0[1]);
    int A23 = pack_f16(e0[2], e0[3]);
    int B01 = pack_f16(e1[0], e1[1]);
    int B23 = pack_f16(e1[2], e1[3]);
    const int s1l = ((lane & 16) << 1) + lm;
    const int s2l = s1l + 16;
    int t0a = __shfl(A01, s1l), t0b = __shfl(B01, s1l);
    int t1a = __shfl(A23, s1l), t1b = __shfl(B23, s1l);
    int t2a = __shfl(A01, s2l), t2b = __shfl(B01, s2l);
    int t3a = __shfl(A23, s2l), t3b = __shfl(B23, s2l);
    union { int i[4]; half8 h; } pau;
    const bool hi = lane >= 32;
    pau.i[0] = hi ? t0b : t0a;
    pau.i[1] = hi ? t1b : t1a;
    pau.i[2] = hi ? t2b : t2a;
    pau.i[3] = hi ? t3b : t3a;
    paP = pau.h;

    BARRIER();   // all waves done reading kbuf[t&1] / vbuf[(t-1)&1]
  }

  // ---- epilogue: PV(63) ----
  WAITVM0();    // V(63) landed (own share)
  BARRIER();    // all waves' shares landed
  {
    const f16* vbp = &lds[16384 + 8192];   // vbuf[63 & 1 = 1]
#pragma unroll
    for (int f = 0; f < 16; ++f) {
      int d = f * 16 + lm;
      half8 bv = *(const half8*)(vbp + d * 32 + ((g ^ ((d >> 1) & 3)) << 3));
      o[f] = MFMA_F16(paP, bv, o[f]);
    }
  }

  float inv[4];
#pragma unroll
  for (int r = 0; r < 4; ++r) inv[r] = 1.0f / __shfl(l, ((lane >> 2) & 12) + r);
#pragma unroll
  for (int f = 0; f < 16; ++f)
#pragma unroll
    for (int r = 0; r < 4; ++r)
      attn[(size_t)(b * 2048 + q0 + g * 4 + r) * 1024 + h * 256 + f * 16 + lm] =
          (f16)(o[f][r] * inv[r]);
}

// ======================= Spectral v4: packed real channels, mixed radix-2/4 FFT =======================
__device__ inline float2 cmul(float2 a, float2 b) {
  return make_float2(a.x * b.x - a.y * b.y, a.x * b.y + a.y * b.x);
}
__device__ inline float2 cmulc(float2 a, float2 b) {   // a * conj(b)
  return make_float2(a.x * b.x + a.y * b.y, a.y * b.x - a.x * b.y);
}
__device__ inline void qcube(float2& w, float2& x, float2& y, float2& z, float2 f) {
  w = cmul(w, f); x = cmul(x, f); y = cmul(y, f); z = cmul(z, f);
  float2 a2 = cmul(w, w);
  float2 sx = cmul(x, x), sy = cmul(y, y), sz = cmul(z, z);
  float2 s = make_float2(sx.x + sy.x + sz.x, sx.y + sy.y + sz.y);
  float2 t3 = make_float2(a2.x - 3.f * s.x, a2.y - 3.f * s.y);
  float2 cf = make_float2(3.f * a2.x - s.x, 3.f * a2.y - s.y);
  w = cmul(w, t3); x = cmul(cf, x); y = cmul(cf, y); z = cmul(cf, z);
}

// frequency k -> storage position after [radix-2, then 5x radix-4] DIF:
// p10 = k&1; remaining 5 bit-pairs of k>>1 reversed pairwise.
__device__ inline int fftpos(int k) {
  int kp = k >> 1;
  return ((k & 1) << 10) | ((kp & 3) << 8) | ((kp & 12) << 4) | (kp & 48)
       | ((kp >> 4) & 12) | ((kp >> 8) & 3);
}

__global__ __launch_bounds__(256)
void spectral4(const float* __restrict__ chol, const float* __restrict__ xin,
               float* __restrict__ outp) {
  __shared__ __align__(16) float2 Z[2][2048];   // 32 KB
  __shared__ float2 tw[1024];                   // 8 KB -> 40 KB, 4 blocks/CU
  const int tid = threadIdx.x;
  const int b = blockIdx.x >> 8;
  const int qd = blockIdx.x & 255;
  const size_t c0 = (size_t)qd * 4;
  const float* cb = chol + (size_t)b * 2048 * 1024;

  for (int j = tid; j < 1024; j += 256) {
    float ang = -6.2831853071795864769f * (float)j * (1.0f / 2048.0f);
    float sv, cv; sincosf(ang, &sv, &cv);
    tw[j] = make_float2(cv, sv);
  }
  for (int s = tid; s < 2048; s += 256) {
    float4 v = *(const float4*)(cb + (size_t)s * 1024 + c0);
    Z[0][s] = make_float2(v.x, v.y);
    Z[1][s] = make_float2(v.z, v.w);
  }
  __syncthreads();

  // ---- forward radix-2 stage (half = 1024) ----
#pragma unroll 1
  for (int it = 0; it < 8; ++it) {
    int gg = it * 256 + tid;
    int c = gg >> 10, j = gg & 1023;
    float2 a = Z[c][j], bb = Z[c][j + 1024];
    Z[c][j] = make_float2(a.x + bb.x, a.y + bb.y);
    Z[c][j + 1024] = cmul(make_float2(a.x - bb.x, a.y - bb.y), tw[j]);
  }
  __syncthreads();

  // ---- forward radix-4 stages Q = 256,64,16,4,1 ----
#pragma unroll 1
  for (int lq = 8; lq >= 0; lq -= 2) {
    const int Q = 1 << lq, st = 512 >> lq;
#pragma unroll 1
    for (int it = 0; it < 4; ++it) {
      int gg = it * 256 + tid;             // 2 arrays x 512 butterflies
      int c = gg >> 9, bf = gg & 511;
      int j = bf & (Q - 1);
      int base = ((bf >> lq) << (lq + 2)) | j;
      float2 a = Z[c][base], bq = Z[c][base + Q];
      float2 cc = Z[c][base + 2 * Q], d = Z[c][base + 3 * Q];
      float2 t0 = make_float2(a.x + cc.x, a.y + cc.y);
      float2 t1 = make_float2(a.x - cc.x, a.y - cc.y);
      float2 t2 = make_float2(bq.x + d.x, bq.y + d.y);
      float2 bd = make_float2(bq.x - d.x, bq.y - d.y);
      float2 t3 = make_float2(bd.y, -bd.x);          // -i*(b-d)
      float2 y0 = make_float2(t0.x + t2.x, t0.y + t2.y);
      float2 y1 = make_float2(t1.x + t3.x, t1.y + t3.y);
      float2 y2 = make_float2(t0.x - t2.x, t0.y - t2.y);
      float2 y3 = make_float2(t1.x - t3.x, t1.y - t3.y);
      int i3 = 3 * j * st;
      float sg = (i3 & 1024) ? -1.f : 1.f;
      i3 &= 1023;
      Z[c][base] = y0;
      Z[c][base + Q] = cmul(y1, tw[j * st]);
      Z[c][base + 2 * Q] = cmul(y2, tw[2 * j * st]);
      float2 r3 = cmul(y3, tw[i3]);
      Z[c][base + 3 * Q] = make_float2(r3.x * sg, r3.y * sg);
    }
    __syncthreads();
  }

  // ---- middle: untangle (k, N-k), filter, quaternion cube, retangle ----
#pragma unroll 1
  for (int it = 0; it < 4; ++it) {
    int jj = it * 256 + tid;
    int nrep = (jj == 0) ? 2 : 1;
#pragma unroll 1
    for (int rep = 0; rep < nrep; ++rep) {
      int k  = (jj == 0) ? (rep ? 1024 : 0) : jj;
      int kn = (jj == 0) ? k : 2048 - jj;
      int p  = fftpos(k);
      int pp = fftpos(kn);
      float2 z0p = Z[0][p], z0q = Z[0][pp];
      float2 z1p = Z[1][p], z1q = Z[1][pp];
      float2 wk = make_float2(0.5f * (z0p.x + z0q.x), 0.5f * (z0p.y - z0q.y));
      float2 xk = make_float2(0.5f * (z0p.y + z0q.y), 0.5f * (z0q.x - z0p.x));
      float2 yk = make_float2(0.5f * (z1p.x + z1q.x), 0.5f * (z1p.y - z1q.y));
      float2 zk = make_float2(0.5f * (z1p.y + z1q.y), 0.5f * (z1q.x - z1p.x));
      float2 wn = make_float2(0.5f * (z0q.x + z0p.x), 0.5f * (z0q.y - z0p.y));
      float2 xn = make_float2(0.5f * (z0q.y + z0p.y), 0.5f * (z0p.x - z0q.x));
      float2 yn = make_float2(0.5f * (z1q.x + z1p.x), 0.5f * (z1q.y - z1p.y));
      float2 zn = make_float2(0.5f * (z1q.y + z1p.y), 0.5f * (z1p.x - z1q.x));
      float sk, ck, sn, cn;
      sincosf(1.5f * atanf(logf((float)k + 1e-10f)), &sk, &ck);
      sincosf(1.5f * atanf(logf((float)kn + 1e-10f)), &sn, &cn);
      qcube(wk, xk, yk, zk, make_float2(ck, sk));
      qcube(wn, xn, yn, zn, make_float2(cn, sn));
      Z[0][p]  = make_float2(0.5f * (wk.x + wn.x) - 0.5f * (xk.y - xn.y),
                             0.5f * (wk.y - wn.y) + 0.5f * (xk.x + xn.x));
      Z[0][pp] = make_float2(0.5f * (wn.x + wk.x) - 0.5f * (xn.y - xk.y),
                             0.5f * (wn.y - wk.y) + 0.5f * (xn.x + xk.x));
      Z[1][p]  = make_float2(0.5f * (yk.x + yn.x) - 0.5f * (zk.y - zn.y),
                             0.5f * (yk.y - yn.y) + 0.5f * (zk.x + zn.x));
      Z[1][pp] = make_float2(0.5f * (yn.x + yk.x) - 0.5f * (zn.y - zk.y),
                             0.5f * (yn.y - yk.y) + 0.5f * (zn.x + zk.x));
    }
  }
  __syncthreads();

  // ---- inverse radix-4 stages Q = 1,4,16,64,256 (conj twiddles) ----
#pragma unroll 1
  for (int lq = 0; lq <= 8; lq += 2) {
    const int Q = 1 << lq, st = 512 >> lq;
#pragma unroll 1
    for (int it = 0; it < 4; ++it) {
      int gg = it * 256 + tid;
      int c = gg >> 9, bf = gg & 511;
      int j = bf & (Q - 1);
      int base = ((bf >> lq) << (lq + 2)) | j;
      float2 a = Z[c][base];
      float2 bq = cmulc(Z[c][base + Q], tw[j * st]);
      float2 cc = cmulc(Z[c][base + 2 * Q], tw[2 * j * st]);
      int i3 = 3 * j * st;
      float sg = (i3 & 1024) ? -1.f : 1.f;
      i3 &= 1023;
      float2 d = cmulc(Z[c][base + 3 * Q], tw[i3]);
      d = make_float2(d.x * sg, d.y * sg);
      float2 t0 = make_float2(a.x + cc.x, a.y + cc.y);
      float2 t1 = make_float2(a.x - cc.x, a.y - cc.y);
      float2 t2 = make_float2(bq.x + d.x, bq.y + d.y);
      float2 bd = make_float2(bq.x - d.x, bq.y - d.y);
      float2 t3 = make_float2(-bd.y, bd.x);          // +i*(b-d)
      Z[c][base]         = make_float2(t0.x + t2.x, t0.y + t2.y);
      Z[c][base + Q]     = make_float2(t1.x + t3.x, t1.y + t3.y);
      Z[c][base + 2 * Q] = make_float2(t0.x - t2.x, t0.y - t2.y);
      Z[c][base + 3 * Q] = make_float2(t1.x - t3.x, t1.y - t3.y);
    }
    __syncthreads();
  }

  // ---- inverse radix-2 stage (half = 1024) ----
#pragma unroll 1
  for (int it = 0; it < 8; ++it) {
    int gg = it * 256 + tid;
    int c = gg >> 10, j = gg & 1023;
    float2 a = Z[c][j];
    float2 bw = cmulc(Z[c][j + 1024], tw[j]);
    Z[c][j] = make_float2(a.x + bw.x, a.y + bw.y);
    Z[c][j + 1024] = make_float2(a.x - bw.x, a.y - bw.y);
  }
  __syncthreads();

  const float* xb = xin + (size_t)b * 2048 * 1024;
  float* ob = outp + (size_t)b * 2048 * 1024;
  const float inv = 1.0f / 2048.0f;
  for (int s = tid; s < 2048; s += 256) {
    float4 xv = *(const float4*)(xb + (size_t)s * 1024 + c0);
    float2 r0 = Z[0][s], r1 = Z[1][s];
    float4 o;
    o.x = xv.x * r0.x * inv;
    o.y = xv.y * r0.y * inv;
    o.z = xv.z * r1.x * inv;
    o.w = xv.w * r1.y * inv;
    *(float4*)(ob + (size_t)s * 1024 + c0) = o;
  }
}

// ======================= launch =======================
extern "C" void kernel_launch(void* const* d_in, const int* in_sizes, int n_in,
                              void* d_out, int out_size, void* d_ws, size_t ws_size,
                              hipStream_t stream) {
  const float* x    = (const float*)d_in[0];
  const float* wqkv = (const float*)d_in[1];
  const float* bqkv = (const float*)d_in[2];
  const float* wout = (const float*)d_in[3];
  const float* bout = (const float*)d_in[4];
  const float* w1   = (const float*)d_in[5];
  const float* b1   = (const float*)d_in[6];
  const float* w2   = (const float*)d_in[7];
  const float* b2   = (const float*)d_in[8];
  float* out = (float*)d_out;
  char* wsb = (char*)d_ws;
  const size_t MB = 1048576;

  f16*   xf    = (f16*)(wsb);              // contiguous conv dst: xf|wqf|wof|w1f|w2f
  f16*   wqf   = (f16*)(wsb + 16 * MB);
  f16*   wof   = (f16*)(wsb + 22 * MB);
  f16*   w1f   = (f16*)(wsb + 24 * MB);
  f16*   w2f   = (f16*)(wsb + 26 * MB);
  f16*   qkvF  = (f16*)(wsb + 28 * MB);
  f16*   VtF   = (f16*)(wsb + 76 * MB);
  f16*   attnF = (f16*)(wsb + 92 * MB);
  float* nico  = (float*)(wsb + 108 * MB);
  f16*   hF    = (f16*)(wsb + 140 * MB);
  float* chol  = (float*)(wsb + 156 * MB);

  conv_all<<<7168, 256, 0, stream>>>(x, wqkv, wout, w1, w2, xf);

  gemm_f16<0, 1><<<dim3(24, 64), 256, 0, stream>>>(xf, wqf, bqkv, qkvF, 3072, 1024, nullptr);
  vtrans<<<512, 256, 0, stream>>>(qkvF, VtF);
  flash_f16<<<512, 256, 0, stream>>>(qkvF, VtF, attnF);
  gemm_f16<0, 0><<<dim3(8, 64), 256, 0, stream>>>(attnF, wof, bout, nico, 1024, 1024, nullptr);
  gemm_f16<1, 1><<<dim3(8, 64), 256, 0, stream>>>(xf, w1f, b1, hF, 1024, 1024, nullptr);
  gemm_f16<2, 0><<<dim3(8, 64), 256, 0, stream>>>(hF, w2f, b2, chol, 1024, 1024, nico);
  spectral4<<<1024, 256, 0, stream>>>(chol, x, out);
}

// Round 9
// 401.476 us; speedup vs baseline: 1.5558x; 1.0378x over previous
//
#include <hip/hip_runtime.h>
#include <cstdint>

// B=4, S=2048, E=1024, H=4, DH=256, DQ=256
typedef _Float16 f16;
typedef unsigned short u16;
typedef __attribute__((ext_vector_type(8))) _Float16 half8;
typedef __attribute__((ext_vector_type(2))) __fp16 fp16x2;
typedef __attribute__((ext_vector_type(4))) float f32x4;

#define MFMA_F16(a, b, c) __builtin_amdgcn_mfma_f32_16x16x32_f16(a, b, c, 0, 0, 0)

#define WAITVM8() asm volatile("s_waitcnt vmcnt(8)" ::: "memory")
#define WAITVM4() asm volatile("s_waitcnt vmcnt(4)" ::: "memory")
#define WAITVM0() asm volatile("s_waitcnt vmcnt(0)" ::: "memory")
#define BARRIER() do { asm volatile("" ::: "memory"); __builtin_amdgcn_s_barrier(); \
                       asm volatile("" ::: "memory"); } while (0)

__device__ inline void stage16(const void* g, void* l) {
#if defined(__has_builtin) && __has_builtin(__builtin_amdgcn_global_load_lds)
  __builtin_amdgcn_global_load_lds(
      (const __attribute__((address_space(1))) unsigned*)g,
      (__attribute__((address_space(3))) unsigned*)l, 16, 0, 0);
#else
  *(int4*)l = *(const int4*)g;
#endif
}

__device__ inline int pack_f16(float a, float b) {
#if defined(__has_builtin) && __has_builtin(__builtin_amdgcn_cvt_pkrtz)
  union { fp16x2 h; int i; } u;
  u.h = __builtin_amdgcn_cvt_pkrtz(a, b);
  return u.i;
#else
  union { f16 h[2]; int i; } u;
  u.h[0] = (f16)a; u.h[1] = (f16)b;
  return u.i;
#endif
}

// ======================= fused fp32 -> fp16 conversion + weight layout =======================
// dst (f16 units): xf[0,8388608) | Wcat2 rows: wqkv[8388608,11534336) + w1[11534336,12582912)
//                  | Wcat [12582912, 16777216): row j stride 2048: [0..1023]=1.8*Wout, [1024..2047]=0.2*W2
__global__ __launch_bounds__(256)
void conv_all(const float* __restrict__ x, const float* __restrict__ wqkv,
              const float* __restrict__ w1, const float* __restrict__ wout,
              const float* __restrict__ w2, f16* __restrict__ dst) {
  int i = (blockIdx.x * 256 + threadIdx.x) * 8;
  const float* src; size_t dofs; float sc = 1.0f;
  if (i < 8388608)       { src = x + i;               dofs = i; }
  else if (i < 11534336) { src = wqkv + (i - 8388608); dofs = i; }
  else if (i < 12582912) { src = w1 + (i - 11534336);  dofs = i; }
  else if (i < 13631488) {
    int t = i - 12582912; int j = t >> 10, k = t & 1023;
    src = wout + t; dofs = 12582912 + (size_t)j * 2048 + k; sc = 1.8f;
  } else {
    int t = i - 13631488; int j = t >> 10, k = t & 1023;
    src = w2 + t; dofs = 12582912 + (size_t)j * 2048 + 1024 + k; sc = 0.2f;
  }
  float4 a = *(const float4*)src;
  float4 b = *(const float4*)(src + 4);
  half8 h;
  h[0] = (f16)(a.x * sc); h[1] = (f16)(a.y * sc); h[2] = (f16)(a.z * sc); h[3] = (f16)(a.w * sc);
  h[4] = (f16)(b.x * sc); h[5] = (f16)(b.y * sc); h[6] = (f16)(b.z * sc); h[7] = (f16)(b.w * sc);
  *(half8*)(dst + dofs) = h;
}

// ======================= fp16 MFMA GEMM, counted-vmcnt 2-phase =======================
// EPI=3: A=xf, W=[Wqkv;W1] N=4096: cols<3072 -> +bqkv -> qkvF(f16, stride 3072);
//        cols>=3072 -> +b1, GELU -> cat[row][1024+c'] (f16, stride 2048)
// EPI=4: A=cat(K=2048), W=Wcat: out chol fp32 = acc + 1.8*bout + 0.2*b2 (stride 1024)
template<int EPI>
__global__ __launch_bounds__(256, 2)
void gemm_f16(const f16* __restrict__ A, const f16* __restrict__ W,
              const float* __restrict__ bias0, const float* __restrict__ bias1,
              void* __restrict__ out0, void* __restrict__ out1, int N, int K) {
  __shared__ __align__(16) f16 lds[2][16384];
  const int tid = threadIdx.x;
  const int lane = tid & 63, w = tid >> 6;
  const int g = lane >> 4, lm = lane & 15;
  const int wr = w >> 1, wc = w & 1;
  const int m0 = blockIdx.y * 128, n0 = blockIdx.x * 128;

  const f16* src[8];
#pragma unroll
  for (int j = 0; j < 8; ++j) {
    int u = j * 256 + tid;
    if (u < 1024) {
      int row = u >> 3, s = u & 7;
      src[j] = A + (size_t)(m0 + row) * K + ((s ^ (row & 7)) << 3);
    } else {
      int v = u - 1024;
      int row = v >> 3, s = v & 7;
      src[j] = W + (size_t)(n0 + row) * K + ((s ^ (row & 7)) << 3);
    }
  }

  f32x4 acc[4][4];
#pragma unroll
  for (int mt = 0; mt < 4; ++mt)
#pragma unroll
    for (int nt = 0; nt < 4; ++nt) acc[mt][nt] = (f32x4){0.f, 0.f, 0.f, 0.f};

#pragma unroll
  for (int j = 0; j < 8; ++j) stage16(src[j], &lds[0][(j * 256 + tid) * 8]);
  __syncthreads();

  const int KT = K >> 6;
#pragma unroll 1
  for (int t = 0; t < KT; ++t) {
    const f16* bufA = lds[t & 1];
    const f16* bufB = bufA + 8192;
    if (t + 1 < KT) {
#pragma unroll
      for (int j = 0; j < 8; ++j) {
        src[j] += 64;
        stage16(src[j], &lds[(t + 1) & 1][(j * 256 + tid) * 8]);
      }
      WAITVM8();
    } else {
      WAITVM0();
    }
    BARRIER();
#pragma unroll
    for (int ks = 0; ks < 2; ++ks) {
      half8 a[4], b[4];
#pragma unroll
      for (int mt = 0; mt < 4; ++mt) {
        int row = wr * 64 + mt * 16 + lm;
        a[mt] = *(const half8*)(bufA + row * 64 + (((ks * 4 + g) ^ (row & 7)) << 3));
      }
#pragma unroll
      for (int nt = 0; nt < 4; ++nt) {
        int row = wc * 64 + nt * 16 + lm;
        b[nt] = *(const half8*)(bufB + row * 64 + (((ks * 4 + g) ^ (row & 7)) << 3));
      }
#pragma unroll
      for (int mt = 0; mt < 4; ++mt)
#pragma unroll
        for (int nt = 0; nt < 4; ++nt)
          acc[mt][nt] = MFMA_F16(a[mt], b[nt], acc[mt][nt]);
    }
    BARRIER();
  }

  const int crow = m0 + wr * 64 + g * 4;
  const int ccol = n0 + wc * 64 + lm;
  if (EPI == 3) {
    if (n0 < 3072) {                       // qkv region (block-uniform)
      f16* qk = (f16*)out0;
#pragma unroll
      for (int nt = 0; nt < 4; ++nt) {
        float bb = bias0[ccol + nt * 16];
#pragma unroll
        for (int mt = 0; mt < 4; ++mt)
#pragma unroll
          for (int r = 0; r < 4; ++r)
            qk[(size_t)(crow + mt * 16 + r) * 3072 + ccol + nt * 16] =
                (f16)(acc[mt][nt][r] + bb);
      }
    } else {                               // h region -> GELU -> cat high half
      f16* cat = (f16*)out1;
      const int hc = ccol - 3072;
#pragma unroll
      for (int nt = 0; nt < 4; ++nt) {
        float bb = bias1[hc + nt * 16];
#pragma unroll
        for (int mt = 0; mt < 4; ++mt)
#pragma unroll
          for (int r = 0; r < 4; ++r) {
            float v = acc[mt][nt][r] + bb;
            v = 0.5f * v * (1.0f + erff(v * 0.70710678118654752f));
            cat[(size_t)(crow + mt * 16 + r) * 2048 + 1024 + hc + nt * 16] = (f16)v;
          }
      }
    }
  } else {                                 // EPI 4: chol fp32
    float* ch = (float*)out0;
#pragma unroll
    for (int nt = 0; nt < 4; ++nt) {
      float bb = 1.8f * bias0[ccol + nt * 16] + 0.2f * bias1[ccol + nt * 16];
#pragma unroll
      for (int mt = 0; mt < 4; ++mt)
#pragma unroll
        for (int r = 0; r < 4; ++r)
          ch[(size_t)(crow + mt * 16 + r) * 1024 + ccol + nt * 16] =
              acc[mt][nt][r] + bb;
    }
  }
}

// ======================= V transpose (unchanged) =======================
__global__ __launch_bounds__(256)
void vtrans(const f16* __restrict__ qkv, f16* __restrict__ Vt) {
  __shared__ unsigned vlds[64][65];
  const int tid = threadIdx.x;
  const int bh = blockIdx.x >> 5, st = blockIdx.x & 31;
  const int b = bh >> 2, h = bh & 3;
  const int s0 = st * 64;
  const u16* q16 = (const u16*)qkv;
  u16* v16 = (u16*)Vt;
#pragma unroll 1
  for (int dc = 0; dc < 4; ++dc) {
    __syncthreads();
#pragma unroll 1
    for (int i = 0; i < 16; ++i) {
      int idx = i * 256 + tid;
      int s = idx >> 6, dl = idx & 63;
      vlds[dl][s] = q16[(size_t)(b * 2048 + s0 + s) * 3072 + 2048 + h * 256 + dc * 64 + dl];
    }
    __syncthreads();
#pragma unroll 1
    for (int i = 0; i < 16; ++i) {
      int idx = i * 256 + tid;
      int dl = idx >> 6, s = idx & 63;
      v16[((size_t)bh * 256 + dc * 64 + dl) * 2048 + s0 + s] = (u16)vlds[dl][s];
    }
  }
}

// ======================= fp16 flash attention v5 (unchanged; output stride 2048) =======================
__global__ __launch_bounds__(256, 2)
void flash_f16(const f16* __restrict__ qkv, const f16* __restrict__ Vt,
               f16* __restrict__ attn) {
  __shared__ __align__(16) f16 lds[32768];   // K[2][32][256] @0, V[2][256][32] @16384
  const int tid = threadIdx.x;
  const int lane = tid & 63, w = tid >> 6;
  const int g = lane >> 4, lm = lane & 15;
  const int raw = blockIdx.x;
  const int bh = (raw & 7) * 2 + (raw >> 8);
  const int qt = (raw >> 3) & 31;
  const int b = bh >> 2, h = bh & 3;
  const int q0 = qt * 64 + w * 16;
  const float SC = 0.09016844005555896f;   // log2(e)/16

  half8 qf[8];
  {
    const f16* qp = qkv + (size_t)(b * 2048 + q0 + lm) * 3072 + h * 256 + g * 8;
#pragma unroll
    for (int c = 0; c < 8; ++c) qf[c] = *(const half8*)(qp + c * 32);
  }

  const f16* kbase = qkv + (size_t)b * 2048 * 3072 + 1024 + h * 256;
  const f16* vbase = Vt + (size_t)bh * 256 * 2048;
  int kofs[4], vofs[4];
#pragma unroll
  for (int j = 0; j < 4; ++j) {
    int u = j * 256 + tid;
    int kv = u >> 5, s = u & 31;
    kofs[j] = kv * 3072 + ((s ^ (kv & 7)) << 3);
    int d = u >> 2, sl = u & 3;
    vofs[j] = d * 2048 + ((sl ^ ((d >> 1) & 3)) << 3);
  }

  f32x4 o[16];
#pragma unroll
  for (int f = 0; f < 16; ++f) o[f] = (f32x4){0.f, 0.f, 0.f, 0.f};
  float m = -3e38f, l = 0.f;
  half8 paP = (half8){0, 0, 0, 0, 0, 0, 0, 0};

#pragma unroll
  for (int j = 0; j < 4; ++j) stage16(kbase + kofs[j], &lds[(j * 256 + tid) * 8]);

#pragma unroll 1
  for (int t = 0; t < 64; ++t) {
    const int cb_ = t & 1;
    if (t < 63) {
      const int kt = (t + 1) * 98304;
#pragma unroll
      for (int j = 0; j < 4; ++j)
        stage16(kbase + kofs[j] + kt, &lds[(cb_ ^ 1) * 8192 + (j * 256 + tid) * 8]);
    }
    {
      const int vt_ = t * 32;
#pragma unroll
      for (int j = 0; j < 4; ++j)
        stage16(vbase + vofs[j] + vt_, &lds[16384 + cb_ * 8192 + (j * 256 + tid) * 8]);
    }
    if (t < 63) { WAITVM8(); } else { WAITVM4(); }
    BARRIER();

    const f16* kb = &lds[cb_ * 8192];

    f32x4 s0 = {0.f, 0.f, 0.f, 0.f}, s1 = {0.f, 0.f, 0.f, 0.f};
    __builtin_amdgcn_s_setprio(1);
#pragma unroll
    for (int c = 0; c < 8; ++c) {
      int slot = ((c * 4 + g) ^ (lm & 7)) << 3;
      half8 b0 = *(const half8*)(kb + lm * 256 + slot);
      half8 b1 = *(const half8*)(kb + (16 + lm) * 256 + slot);
      s0 = MFMA_F16(b0, qf[c], s0);
      s1 = MFMA_F16(b1, qf[c], s1);
    }
    __builtin_amdgcn_s_setprio(0);

    if (t > 0) {
      const f16* vbp = &lds[16384 + (cb_ ^ 1) * 8192];
      __builtin_amdgcn_s_setprio(1);
#pragma unroll
      for (int f = 0; f < 16; ++f) {
        int d = f * 16 + lm;
        half8 bv = *(const half8*)(vbp + d * 32 + ((g ^ ((d >> 1) & 3)) << 3));
        o[f] = MFMA_F16(paP, bv, o[f]);
      }
      __builtin_amdgcn_s_setprio(0);
    }

    float a0[4], a1[4];
#pragma unroll
    for (int r = 0; r < 4; ++r) { a0[r] = s0[r] * SC; a1[r] = s1[r] * SC; }
    float mx = fmaxf(fmaxf(fmaxf(a0[0], a0[1]), fmaxf(a0[2], a0[3])),
                     fmaxf(fmaxf(a1[0], a1[1]), fmaxf(a1[2], a1[3])));
    mx = fmaxf(mx, __shfl_xor(mx, 16));
    mx = fmaxf(mx, __shfl_xor(mx, 32));

    if (!__all(mx <= m + 8.0f)) {
      float mn = fmaxf(m, mx);
      float corr = exp2f(m - mn);
      m = mn; l *= corr;
#pragma unroll
      for (int r = 0; r < 4; ++r) {
        float cr = __shfl(corr, ((lane >> 2) & 12) + r);
#pragma unroll
        for (int f = 0; f < 16; ++f) o[f][r] *= cr;
      }
    }

    float e0[4], e1[4], rs;
#pragma unroll
    for (int r = 0; r < 4; ++r) { e0[r] = exp2f(a0[r] - m); e1[r] = exp2f(a1[r] - m); }
    rs = ((e0[0] + e0[1]) + (e0[2] + e0[3])) + ((e1[0] + e1[1]) + (e1[2] + e1[3]));
    rs += __shfl_xor(rs, 16);
    rs += __shfl_xor(rs, 32);
    l += rs;

    int A01 = pack_f16(e0[0], e0[1]);
    int A23 = pack_f16(e0[2], e0[3]);
    int B01 = pack_f16(e1[0], e1[1]);
    int B23 = pack_f16(e1[2], e1[3]);
    const int s1l = ((lane & 16) << 1) + lm;
    const int s2l = s1l + 16;
    int t0a = __shfl(A01, s1l), t0b = __shfl(B01, s1l);
    int t1a = __shfl(A23, s1l), t1b = __shfl(B23, s1l);
    int t2a = __shfl(A01, s2l), t2b = __shfl(B01, s2l);
    int t3a = __shfl(A23, s2l), t3b = __shfl(B23, s2l);
    union { int i[4]; half8 h; } pau;
    const bool hi = lane >= 32;
    pau.i[0] = hi ? t0b : t0a;
    pau.i[1] = hi ? t1b : t1a;
    pau.i[2] = hi ? t2b : t2a;
    pau.i[3] = hi ? t3b : t3a;
    paP = pau.h;

    BARRIER();
  }

  WAITVM0();
  BARRIER();
  {
    const f16* vbp = &lds[16384 + 8192];
#pragma unroll
    for (int f = 0; f < 16; ++f) {
      int d = f * 16 + lm;
      half8 bv = *(const half8*)(vbp + d * 32 + ((g ^ ((d >> 1) & 3)) << 3));
      o[f] = MFMA_F16(paP, bv, o[f]);
    }
  }

  float inv[4];
#pragma unroll
  for (int r = 0; r < 4; ++r) inv[r] = 1.0f / __shfl(l, ((lane >> 2) & 12) + r);
#pragma unroll
  for (int f = 0; f < 16; ++f)
#pragma unroll
    for (int r = 0; r < 4; ++r)
      attn[(size_t)(b * 2048 + q0 + g * 4 + r) * 2048 + h * 256 + f * 16 + lm] =
          (f16)(o[f][r] * inv[r]);
}

// ======================= Spectral v4 (unchanged) =======================
__device__ inline float2 cmul(float2 a, float2 b) {
  return make_float2(a.x * b.x - a.y * b.y, a.x * b.y + a.y * b.x);
}
__device__ inline float2 cmulc(float2 a, float2 b) {
  return make_float2(a.x * b.x + a.y * b.y, a.y * b.x - a.x * b.y);
}
__device__ inline void qcube(float2& w, float2& x, float2& y, float2& z, float2 f) {
  w = cmul(w, f); x = cmul(x, f); y = cmul(y, f); z = cmul(z, f);
  float2 a2 = cmul(w, w);
  float2 sx = cmul(x, x), sy = cmul(y, y), sz = cmul(z, z);
  float2 s = make_float2(sx.x + sy.x + sz.x, sx.y + sy.y + sz.y);
  float2 t3 = make_float2(a2.x - 3.f * s.x, a2.y - 3.f * s.y);
  float2 cf = make_float2(3.f * a2.x - s.x, 3.f * a2.y - s.y);
  w = cmul(w, t3); x = cmul(cf, x); y = cmul(cf, y); z = cmul(cf, z);
}

__device__ inline int fftpos(int k) {
  int kp = k >> 1;
  return ((k & 1) << 10) | ((kp & 3) << 8) | ((kp & 12) << 4) | (kp & 48)
       | ((kp >> 4) & 12) | ((kp >> 8) & 3);
}

__global__ __launch_bounds__(256)
void spectral4(const float* __restrict__ chol, const float* __restrict__ xin,
               float* __restrict__ outp) {
  __shared__ __align__(16) float2 Z[2][2048];
  __shared__ float2 tw[1024];
  const int tid = threadIdx.x;
  const int b = blockIdx.x >> 8;
  const int qd = blockIdx.x & 255;
  const size_t c0 = (size_t)qd * 4;
  const float* cb = chol + (size_t)b * 2048 * 1024;

  for (int j = tid; j < 1024; j += 256) {
    float ang = -6.2831853071795864769f * (float)j * (1.0f / 2048.0f);
    float sv, cv; sincosf(ang, &sv, &cv);
    tw[j] = make_float2(cv, sv);
  }
  for (int s = tid; s < 2048; s += 256) {
    float4 v = *(const float4*)(cb + (size_t)s * 1024 + c0);
    Z[0][s] = make_float2(v.x, v.y);
    Z[1][s] = make_float2(v.z, v.w);
  }
  __syncthreads();

#pragma unroll 1
  for (int it = 0; it < 8; ++it) {
    int gg = it * 256 + tid;
    int c = gg >> 10, j = gg & 1023;
    float2 a = Z[c][j], bb = Z[c][j + 1024];
    Z[c][j] = make_float2(a.x + bb.x, a.y + bb.y);
    Z[c][j + 1024] = cmul(make_float2(a.x - bb.x, a.y - bb.y), tw[j]);
  }
  __syncthreads();

#pragma unroll 1
  for (int lq = 8; lq >= 0; lq -= 2) {
    const int Q = 1 << lq, st = 512 >> lq;
#pragma unroll 1
    for (int it = 0; it < 4; ++it) {
      int gg = it * 256 + tid;
      int c = gg >> 9, bf = gg & 511;
      int j = bf & (Q - 1);
      int base = ((bf >> lq) << (lq + 2)) | j;
      float2 a = Z[c][base], bq = Z[c][base + Q];
      float2 cc = Z[c][base + 2 * Q], d = Z[c][base + 3 * Q];
      float2 t0 = make_float2(a.x + cc.x, a.y + cc.y);
      float2 t1 = make_float2(a.x - cc.x, a.y - cc.y);
      float2 t2 = make_float2(bq.x + d.x, bq.y + d.y);
      float2 bd = make_float2(bq.x - d.x, bq.y - d.y);
      float2 t3 = make_float2(bd.y, -bd.x);
      float2 y0 = make_float2(t0.x + t2.x, t0.y + t2.y);
      float2 y1 = make_float2(t1.x + t3.x, t1.y + t3.y);
      float2 y2 = make_float2(t0.x - t2.x, t0.y - t2.y);
      float2 y3 = make_float2(t1.x - t3.x, t1.y - t3.y);
      int i3 = 3 * j * st;
      float sg = (i3 & 1024) ? -1.f : 1.f;
      i3 &= 1023;
      Z[c][base] = y0;
      Z[c][base + Q] = cmul(y1, tw[j * st]);
      Z[c][base + 2 * Q] = cmul(y2, tw[2 * j * st]);
      float2 r3 = cmul(y3, tw[i3]);
      Z[c][base + 3 * Q] = make_float2(r3.x * sg, r3.y * sg);
    }
    __syncthreads();
  }

#pragma unroll 1
  for (int it = 0; it < 4; ++it) {
    int jj = it * 256 + tid;
    int nrep = (jj == 0) ? 2 : 1;
#pragma unroll 1
    for (int rep = 0; rep < nrep; ++rep) {
      int k  = (jj == 0) ? (rep ? 1024 : 0) : jj;
      int kn = (jj == 0) ? k : 2048 - jj;
      int p  = fftpos(k);
      int pp = fftpos(kn);
      float2 z0p = Z[0][p], z0q = Z[0][pp];
      float2 z1p = Z[1][p], z1q = Z[1][pp];
      float2 wk = make_float2(0.5f * (z0p.x + z0q.x), 0.5f * (z0p.y - z0q.y));
      float2 xk = make_float2(0.5f * (z0p.y + z0q.y), 0.5f * (z0q.x - z0p.x));
      float2 yk = make_float2(0.5f * (z1p.x + z1q.x), 0.5f * (z1p.y - z1q.y));
      float2 zk = make_float2(0.5f * (z1p.y + z1q.y), 0.5f * (z1q.x - z1p.x));
      float2 wn = make_float2(0.5f * (z0q.x + z0p.x), 0.5f * (z0q.y - z0p.y));
      float2 xn = make_float2(0.5f * (z0q.y + z0p.y), 0.5f * (z0p.x - z0q.x));
      float2 yn = make_float2(0.5f * (z1q.x + z1p.x), 0.5f * (z1q.y - z1p.y));
      float2 zn = make_float2(0.5f * (z1q.y + z1p.y), 0.5f * (z1p.x - z1q.x));
      float sk, ck, sn, cn;
      sincosf(1.5f * atanf(logf((float)k + 1e-10f)), &sk, &ck);
      sincosf(1.5f * atanf(logf((float)kn + 1e-10f)), &sn, &cn);
      qcube(wk, xk, yk, zk, make_float2(ck, sk));
      qcube(wn, xn, yn, zn, make_float2(cn, sn));
      Z[0][p]  = make_float2(0.5f * (wk.x + wn.x) - 0.5f * (xk.y - xn.y),
                             0.5f * (wk.y - wn.y) + 0.5f * (xk.x + xn.x));
      Z[0][pp] = make_float2(0.5f * (wn.x + wk.x) - 0.5f * (xn.y - xk.y),
                             0.5f * (wn.y - wk.y) + 0.5f * (xn.x + xk.x));
      Z[1][p]  = make_float2(0.5f * (yk.x + yn.x) - 0.5f * (zk.y - zn.y),
                             0.5f * (yk.y - yn.y) + 0.5f * (zk.x + zn.x));
      Z[1][pp] = make_float2(0.5f * (yn.x + yk.x) - 0.5f * (zn.y - zk.y),
                             0.5f * (yn.y - yk.y) + 0.5f * (zn.x + zk.x));
    }
  }
  __syncthreads();

#pragma unroll 1
  for (int lq = 0; lq <= 8; lq += 2) {
    const int Q = 1 << lq, st = 512 >> lq;
#pragma unroll 1
    for (int it = 0; it < 4; ++it) {
      int gg = it * 256 + tid;
      int c = gg >> 9, bf = gg & 511;
      int j = bf & (Q - 1);
      int base = ((bf >> lq) << (lq + 2)) | j;
      float2 a = Z[c][base];
      float2 bq = cmulc(Z[c][base + Q], tw[j * st]);
      float2 cc = cmulc(Z[c][base + 2 * Q], tw[2 * j * st]);
      int i3 = 3 * j * st;
      float sg = (i3 & 1024) ? -1.f : 1.f;
      i3 &= 1023;
      float2 d = cmulc(Z[c][base + 3 * Q], tw[i3]);
      d = make_float2(d.x * sg, d.y * sg);
      float2 t0 = make_float2(a.x + cc.x, a.y + cc.y);
      float2 t1 = make_float2(a.x - cc.x, a.y - cc.y);
      float2 t2 = make_float2(bq.x + d.x, bq.y + d.y);
      float2 bd = make_float2(bq.x - d.x, bq.y - d.y);
      float2 t3 = make_float2(-bd.y, bd.x);
      Z[c][base]         = make_float2(t0.x + t2.x, t0.y + t2.y);
      Z[c][base + Q]     = make_float2(t1.x + t3.x, t1.y + t3.y);
      Z[c][base + 2 * Q] = make_float2(t0.x - t2.x, t0.y - t2.y);
      Z[c][base + 3 * Q] = make_float2(t1.x - t3.x, t1.y - t3.y);
    }
    __syncthreads();
  }

#pragma unroll 1
  for (int it = 0; it < 8; ++it) {
    int gg = it * 256 + tid;
    int c = gg >> 10, j = gg & 1023;
    float2 a = Z[c][j];
    float2 bw = cmulc(Z[c][j + 1024], tw[j]);
    Z[c][j] = make_float2(a.x + bw.x, a.y + bw.y);
    Z[c][j + 1024] = make_float2(a.x - bw.x, a.y - bw.y);
  }
  __syncthreads();

  const float* xb = xin + (size_t)b * 2048 * 1024;
  float* ob = outp + (size_t)b * 2048 * 1024;
  const float inv = 1.0f / 2048.0f;
  for (int s = tid; s < 2048; s += 256) {
    float4 xv = *(const float4*)(xb + (size_t)s * 1024 + c0);
    float2 r0 = Z[0][s], r1 = Z[1][s];
    float4 o;
    o.x = xv.x * r0.x * inv;
    o.y = xv.y * r0.y * inv;
    o.z = xv.z * r1.x * inv;
    o.w = xv.w * r1.y * inv;
    *(float4*)(ob + (size_t)s * 1024 + c0) = o;
  }
}

// ======================= launch =======================
extern "C" void kernel_launch(void* const* d_in, const int* in_sizes, int n_in,
                              void* d_out, int out_size, void* d_ws, size_t ws_size,
                              hipStream_t stream) {
  const float* x    = (const float*)d_in[0];
  const float* wqkv = (const float*)d_in[1];
  const float* bqkv = (const float*)d_in[2];
  const float* wout = (const float*)d_in[3];
  const float* bout = (const float*)d_in[4];
  const float* w1   = (const float*)d_in[5];
  const float* b1   = (const float*)d_in[6];
  const float* w2   = (const float*)d_in[7];
  const float* b2   = (const float*)d_in[8];
  float* out = (float*)d_out;
  char* wsb = (char*)d_ws;
  const size_t MB = 1048576;

  // ws layout: xf 16MB@0 | Wcat2 (wqkv+w1) 8MB@16 | Wcat 8MB@24 | qkvF 48MB@32
  //          | VtF 16MB@80 | cat (attn||h, stride 2048) 32MB@96 | chol 32MB@128
  f16*   xf    = (f16*)(wsb);
  f16*   wqf   = (f16*)(wsb + 16 * MB);      // rows 0..4095 (Wqkv then W1)
  f16*   wcat  = (f16*)(wsb + 24 * MB);      // [1024][2048]: 1.8*Wout | 0.2*W2
  f16*   qkvF  = (f16*)(wsb + 32 * MB);
  f16*   VtF   = (f16*)(wsb + 80 * MB);
  f16*   cat   = (f16*)(wsb + 96 * MB);
  float* chol  = (float*)(wsb + 128 * MB);

  conv_all<<<7168, 256, 0, stream>>>(x, wqkv, w1, wout, w2, xf);

  // GEMM A: [qkv | gelu(h)] = xf @ [Wqkv;W1]^T  (N=4096, K=1024)
  gemm_f16<3><<<dim3(32, 64), 256, 0, stream>>>(xf, wqf, bqkv, b1, qkvF, cat, 4096, 1024);
  vtrans<<<512, 256, 0, stream>>>(qkvF, VtF);
  flash_f16<<<512, 256, 0, stream>>>(qkvF, VtF, cat);   // writes cat low half
  // GEMM B: chol2 = [attn|h] @ [1.8Wout|0.2W2]^T + 1.8bout + 0.2b2  (N=1024, K=2048)
  gemm_f16<4><<<dim3(8, 64), 256, 0, stream>>>(cat, wcat, bout, b2, chol, nullptr, 1024, 2048);
  spectral4<<<1024, 256, 0, stream>>>(chol, x, out);
}

// Round 10
// 360.647 us; speedup vs baseline: 1.7320x; 1.1132x over previous
//
#include <hip/hip_runtime.h>
#include <cstdint>

// B=4, S=2048, E=1024, H=4, DH=256, DQ=256
typedef _Float16 f16;
typedef unsigned short u16;
typedef __attribute__((ext_vector_type(8))) _Float16 half8;
typedef __attribute__((ext_vector_type(4))) _Float16 half4;
typedef __attribute__((ext_vector_type(2))) __fp16 fp16x2;
typedef __attribute__((ext_vector_type(4))) float f32x4;

#define MFMA_F16(a, b, c) __builtin_amdgcn_mfma_f32_16x16x32_f16(a, b, c, 0, 0, 0)

#define WAITVM8() asm volatile("s_waitcnt vmcnt(8)" ::: "memory")
#define WAITVM4() asm volatile("s_waitcnt vmcnt(4)" ::: "memory")
#define WAITVM2() asm volatile("s_waitcnt vmcnt(2)" ::: "memory")
#define WAITVM0() asm volatile("s_waitcnt vmcnt(0)" ::: "memory")
#define BARRIER() do { asm volatile("" ::: "memory"); __builtin_amdgcn_s_barrier(); \
                       asm volatile("" ::: "memory"); } while (0)

__device__ inline void stage16(const void* g, void* l) {
#if defined(__has_builtin) && __has_builtin(__builtin_amdgcn_global_load_lds)
  __builtin_amdgcn_global_load_lds(
      (const __attribute__((address_space(1))) unsigned*)g,
      (__attribute__((address_space(3))) unsigned*)l, 16, 0, 0);
#else
  *(int4*)l = *(const int4*)g;
#endif
}

__device__ inline int pack_f16(float a, float b) {
#if defined(__has_builtin) && __has_builtin(__builtin_amdgcn_cvt_pkrtz)
  union { fp16x2 h; int i; } u;
  u.h = __builtin_amdgcn_cvt_pkrtz(a, b);
  return u.i;
#else
  union { f16 h[2]; int i; } u;
  u.h[0] = (f16)a; u.h[1] = (f16)b;
  return u.i;
#endif
}

// ======================= fused fp32 -> fp16 conversion + weight layout =======================
__global__ __launch_bounds__(256)
void conv_all(const float* __restrict__ x, const float* __restrict__ wqkv,
              const float* __restrict__ w1, const float* __restrict__ wout,
              const float* __restrict__ w2, f16* __restrict__ dst) {
  int i = (blockIdx.x * 256 + threadIdx.x) * 8;
  const float* src; size_t dofs; float sc = 1.0f;
  if (i < 8388608)       { src = x + i;               dofs = i; }
  else if (i < 11534336) { src = wqkv + (i - 8388608); dofs = i; }
  else if (i < 12582912) { src = w1 + (i - 11534336);  dofs = i; }
  else if (i < 13631488) {
    int t = i - 12582912; int j = t >> 10, k = t & 1023;
    src = wout + t; dofs = 12582912 + (size_t)j * 2048 + k; sc = 1.8f;
  } else {
    int t = i - 13631488; int j = t >> 10, k = t & 1023;
    src = w2 + t; dofs = 12582912 + (size_t)j * 2048 + 1024 + k; sc = 0.2f;
  }
  float4 a = *(const float4*)src;
  float4 b = *(const float4*)(src + 4);
  half8 h;
  h[0] = (f16)(a.x * sc); h[1] = (f16)(a.y * sc); h[2] = (f16)(a.z * sc); h[3] = (f16)(a.w * sc);
  h[4] = (f16)(b.x * sc); h[5] = (f16)(b.y * sc); h[6] = (f16)(b.z * sc); h[7] = (f16)(b.w * sc);
  *(half8*)(dst + dofs) = h;
}

// ======================= fp16 MFMA GEMM, counted-vmcnt 2-phase, XCD-swizzled =======================
// EPI=3: A=xf, W=[Wqkv;W1] N=4096:
//   n0<2048   -> +bqkv -> qkvF (f16, stride 3072)           [Q,K region]
//   n0<3072   -> +bqkv -> TRANSPOSED via LDS -> Vt           [V region]
//   n0>=3072  -> +b1, GELU -> cat[row][1024+c'] (stride 2048)[h region]
// EPI=4: A=cat(K=2048), W=Wcat: chol f16 = acc + 1.8*bout + 0.2*b2 (stride 1024)
template<int EPI>
__global__ __launch_bounds__(256, 2)
void gemm_f16(const f16* __restrict__ A, const f16* __restrict__ W,
              const float* __restrict__ bias0, const float* __restrict__ bias1,
              void* __restrict__ out0, void* __restrict__ out1,
              f16* __restrict__ Vt, int N, int K) {
  __shared__ __align__(16) f16 lds[2][16384];
  const int tid = threadIdx.x;
  const int lane = tid & 63, w = tid >> 6;
  const int g = lane >> 4, lm = lane & 15;
  const int wr = w >> 1, wc = w & 1;
  // bijective XCD swizzle (nwg % 8 == 0): XCD x gets contiguous logical range
  const int nwg = gridDim.x * gridDim.y;
  const int flat = blockIdx.y * gridDim.x + blockIdx.x;
  const int logical = (flat & 7) * (nwg >> 3) + (flat >> 3);
  const int bx = logical % gridDim.x, by = logical / gridDim.x;
  const int m0 = by * 128, n0 = bx * 128;

  const f16* src[8];
#pragma unroll
  for (int j = 0; j < 8; ++j) {
    int u = j * 256 + tid;
    if (u < 1024) {
      int row = u >> 3, s = u & 7;
      src[j] = A + (size_t)(m0 + row) * K + ((s ^ (row & 7)) << 3);
    } else {
      int v = u - 1024;
      int row = v >> 3, s = v & 7;
      src[j] = W + (size_t)(n0 + row) * K + ((s ^ (row & 7)) << 3);
    }
  }

  f32x4 acc[4][4];
#pragma unroll
  for (int mt = 0; mt < 4; ++mt)
#pragma unroll
    for (int nt = 0; nt < 4; ++nt) acc[mt][nt] = (f32x4){0.f, 0.f, 0.f, 0.f};

#pragma unroll
  for (int j = 0; j < 8; ++j) stage16(src[j], &lds[0][(j * 256 + tid) * 8]);
  __syncthreads();

  const int KT = K >> 6;
#pragma unroll 1
  for (int t = 0; t < KT; ++t) {
    const f16* bufA = lds[t & 1];
    const f16* bufB = bufA + 8192;
    if (t + 1 < KT) {
#pragma unroll
      for (int j = 0; j < 8; ++j) {
        src[j] += 64;
        stage16(src[j], &lds[(t + 1) & 1][(j * 256 + tid) * 8]);
      }
      WAITVM8();
    } else {
      WAITVM0();
    }
    BARRIER();
#pragma unroll
    for (int ks = 0; ks < 2; ++ks) {
      half8 a[4], b[4];
#pragma unroll
      for (int mt = 0; mt < 4; ++mt) {
        int row = wr * 64 + mt * 16 + lm;
        a[mt] = *(const half8*)(bufA + row * 64 + (((ks * 4 + g) ^ (row & 7)) << 3));
      }
#pragma unroll
      for (int nt = 0; nt < 4; ++nt) {
        int row = wc * 64 + nt * 16 + lm;
        b[nt] = *(const half8*)(bufB + row * 64 + (((ks * 4 + g) ^ (row & 7)) << 3));
      }
#pragma unroll
      for (int mt = 0; mt < 4; ++mt)
#pragma unroll
        for (int nt = 0; nt < 4; ++nt)
          acc[mt][nt] = MFMA_F16(a[mt], b[nt], acc[mt][nt]);
    }
    BARRIER();
  }

  const int crow = m0 + wr * 64 + g * 4;
  const int ccol = n0 + wc * 64 + lm;
  if (EPI == 3) {
    if (n0 < 2048) {                       // Q,K region -> qkvF rows
      f16* qk = (f16*)out0;
#pragma unroll
      for (int nt = 0; nt < 4; ++nt) {
        float bb = bias0[ccol + nt * 16];
#pragma unroll
        for (int mt = 0; mt < 4; ++mt)
#pragma unroll
          for (int r = 0; r < 4; ++r)
            qk[(size_t)(crow + mt * 16 + r) * 3072 + ccol + nt * 16] =
                (f16)(acc[mt][nt][r] + bb);
      }
    } else if (n0 < 3072) {                // V region -> transposed Vt via LDS
      f16* ldsT = (f16*)lds;               // [128 c][136 r] f16 = 34.8 KB
#pragma unroll
      for (int nt = 0; nt < 4; ++nt) {
        float bb = bias0[ccol + nt * 16];
        int c = wc * 64 + nt * 16 + lm;
#pragma unroll
        for (int mt = 0; mt < 4; ++mt) {
          int r = wr * 64 + mt * 16 + g * 4;
#pragma unroll
          for (int rr = 0; rr < 4; ++rr)
            ldsT[c * 136 + r + rr] = (f16)(acc[mt][nt][rr] + bb);
        }
      }
      BARRIER();
      const int vbase0 = n0 - 2048;
      const int b = m0 >> 11, srow = m0 & 2047;
#pragma unroll
      for (int it = 0; it < 8; ++it) {
        int id = it * 256 + tid;
        int c = id >> 4, rb = id & 15;
        int vcol = vbase0 + c;
        int h = vcol >> 8, d = vcol & 255;
        half8 v = *(half8*)&ldsT[c * 136 + rb * 8];
        *(half8*)&Vt[(((size_t)(b * 4 + h)) * 256 + d) * 2048 + srow + rb * 8] = v;
      }
    } else {                               // h region -> GELU -> cat high half
      f16* cat = (f16*)out1;
      const int hc = ccol - 3072;
#pragma unroll
      for (int nt = 0; nt < 4; ++nt) {
        float bb = bias1[hc + nt * 16];
#pragma unroll
        for (int mt = 0; mt < 4; ++mt)
#pragma unroll
          for (int r = 0; r < 4; ++r) {
            float v = acc[mt][nt][r] + bb;
            v = 0.5f * v * (1.0f + erff(v * 0.70710678118654752f));
            cat[(size_t)(crow + mt * 16 + r) * 2048 + 1024 + hc + nt * 16] = (f16)v;
          }
      }
    }
  } else {                                 // EPI 4: chol f16
    f16* ch = (f16*)out0;
#pragma unroll
    for (int nt = 0; nt < 4; ++nt) {
      float bb = 1.8f * bias0[ccol + nt * 16] + 0.2f * bias1[ccol + nt * 16];
#pragma unroll
      for (int mt = 0; mt < 4; ++mt)
#pragma unroll
        for (int r = 0; r < 4; ++r)
          ch[(size_t)(crow + mt * 16 + r) * 1024 + ccol + nt * 16] =
              (f16)(acc[mt][nt][r] + bb);
    }
  }
}

// ======================= fp16 flash attention v6: 8 waves / BQ=128, grid 256 =======================
// Per iter: stage K(t+1) (2 units/thread) + V(t) (2); QK(t); PV(t-1); softmax(t); counted vmcnt.
__global__ __launch_bounds__(512, 2)
void flash_f16(const f16* __restrict__ qkv, const f16* __restrict__ Vt,
               f16* __restrict__ attn) {
  __shared__ __align__(16) f16 lds[32768];   // K[2][32][256] @0, V[2][256][32] @16384
  const int tid = threadIdx.x;
  const int lane = tid & 63, w = tid >> 6;   // w 0..7
  const int g = lane >> 4, lm = lane & 15;
  const int raw = blockIdx.x;                // 256 blocks
  const int bh = (raw & 7) * 2 + (raw >> 7); // XCD x -> bh {2x, 2x+1}
  const int qt = (raw >> 3) & 15;
  const int b = bh >> 2, h = bh & 3;
  const int q0 = qt * 128 + w * 16;
  const float SC = 0.09016844005555896f;     // log2(e)/16

  half8 qf[8];
  {
    const f16* qp = qkv + (size_t)(b * 2048 + q0 + lm) * 3072 + h * 256 + g * 8;
#pragma unroll
    for (int c = 0; c < 8; ++c) qf[c] = *(const half8*)(qp + c * 32);
  }

  const f16* kbase = qkv + (size_t)b * 2048 * 3072 + 1024 + h * 256;
  const f16* vbase = Vt + (size_t)bh * 256 * 2048;
  int kofs[2], vofs[2];
#pragma unroll
  for (int j = 0; j < 2; ++j) {
    int u = j * 512 + tid;
    int kv = u >> 5, s = u & 31;
    kofs[j] = kv * 3072 + ((s ^ (kv & 7)) << 3);
    int d = u >> 2, sl = u & 3;
    vofs[j] = d * 2048 + ((sl ^ ((d >> 1) & 3)) << 3);
  }

  f32x4 o[16];
#pragma unroll
  for (int f = 0; f < 16; ++f) o[f] = (f32x4){0.f, 0.f, 0.f, 0.f};
  float m = -3e38f, l = 0.f;
  half8 paP = (half8){0, 0, 0, 0, 0, 0, 0, 0};

#pragma unroll
  for (int j = 0; j < 2; ++j) stage16(kbase + kofs[j], &lds[(j * 512 + tid) * 8]);

#pragma unroll 1
  for (int t = 0; t < 64; ++t) {
    const int cb_ = t & 1;
    if (t < 63) {
      const int kt = (t + 1) * 98304;
#pragma unroll
      for (int j = 0; j < 2; ++j)
        stage16(kbase + kofs[j] + kt, &lds[(cb_ ^ 1) * 8192 + (j * 512 + tid) * 8]);
    }
    {
      const int vt_ = t * 32;
#pragma unroll
      for (int j = 0; j < 2; ++j)
        stage16(vbase + vofs[j] + vt_, &lds[16384 + cb_ * 8192 + (j * 512 + tid) * 8]);
    }
    if (t < 63) { WAITVM4(); } else { WAITVM2(); }   // K(t),V(t-1) landed
    BARRIER();

    const f16* kb = &lds[cb_ * 8192];

    // ---- QK(t): S^T[kv][q] = mfma(A=K, B=Q) ----
    f32x4 s0 = {0.f, 0.f, 0.f, 0.f}, s1 = {0.f, 0.f, 0.f, 0.f};
    __builtin_amdgcn_s_setprio(1);
#pragma unroll
    for (int c = 0; c < 8; ++c) {
      int slot = ((c * 4 + g) ^ (lm & 7)) << 3;
      half8 b0 = *(const half8*)(kb + lm * 256 + slot);
      half8 b1 = *(const half8*)(kb + (16 + lm) * 256 + slot);
      s0 = MFMA_F16(b0, qf[c], s0);
      s1 = MFMA_F16(b1, qf[c], s1);
    }
    __builtin_amdgcn_s_setprio(0);

    // ---- PV(t-1) ----
    if (t > 0) {
      const f16* vbp = &lds[16384 + (cb_ ^ 1) * 8192];
      __builtin_amdgcn_s_setprio(1);
#pragma unroll
      for (int f = 0; f < 16; ++f) {
        int d = f * 16 + lm;
        half8 bv = *(const half8*)(vbp + d * 32 + ((g ^ ((d >> 1) & 3)) << 3));
        o[f] = MFMA_F16(paP, bv, o[f]);
      }
      __builtin_amdgcn_s_setprio(0);
    }

    // ---- softmax(t), defer-max (log2 domain) ----
    float a0[4], a1[4];
#pragma unroll
    for (int r = 0; r < 4; ++r) { a0[r] = s0[r] * SC; a1[r] = s1[r] * SC; }
    float mx = fmaxf(fmaxf(fmaxf(a0[0], a0[1]), fmaxf(a0[2], a0[3])),
                     fmaxf(fmaxf(a1[0], a1[1]), fmaxf(a1[2], a1[3])));
    mx = fmaxf(mx, __shfl_xor(mx, 16));
    mx = fmaxf(mx, __shfl_xor(mx, 32));

    if (!__all(mx <= m + 8.0f)) {
      float mn = fmaxf(m, mx);
      float corr = exp2f(m - mn);
      m = mn; l *= corr;
#pragma unroll
      for (int r = 0; r < 4; ++r) {
        float cr = __shfl(corr, ((lane >> 2) & 12) + r);
#pragma unroll
        for (int f = 0; f < 16; ++f) o[f][r] *= cr;
      }
    }

    float e0[4], e1[4], rs;
#pragma unroll
    for (int r = 0; r < 4; ++r) { e0[r] = exp2f(a0[r] - m); e1[r] = exp2f(a1[r] - m); }
    rs = ((e0[0] + e0[1]) + (e0[2] + e0[3])) + ((e1[0] + e1[1]) + (e1[2] + e1[3]));
    rs += __shfl_xor(rs, 16);
    rs += __shfl_xor(rs, 32);
    l += rs;

    int A01 = pack_f16(e0[0], e0[1]);
    int A23 = pack_f16(e0[2], e0[3]);
    int B01 = pack_f16(e1[0], e1[1]);
    int B23 = pack_f16(e1[2], e1[3]);
    const int s1l = ((lane & 16) << 1) + lm;
    const int s2l = s1l + 16;
    int t0a = __shfl(A01, s1l), t0b = __shfl(B01, s1l);
    int t1a = __shfl(A23, s1l), t1b = __shfl(B23, s1l);
    int t2a = __shfl(A01, s2l), t2b = __shfl(B01, s2l);
    int t3a = __shfl(A23, s2l), t3b = __shfl(B23, s2l);
    union { int i[4]; half8 h; } pau;
    const bool hi = lane >= 32;
    pau.i[0] = hi ? t0b : t0a;
    pau.i[1] = hi ? t1b : t1a;
    pau.i[2] = hi ? t2b : t2a;
    pau.i[3] = hi ? t3b : t3a;
    paP = pau.h;

    BARRIER();
  }

  // ---- epilogue: PV(63) ----
  WAITVM0();
  BARRIER();
  {
    const f16* vbp = &lds[16384 + 8192];   // vbuf[63 & 1]
#pragma unroll
    for (int f = 0; f < 16; ++f) {
      int d = f * 16 + lm;
      half8 bv = *(const half8*)(vbp + d * 32 + ((g ^ ((d >> 1) & 3)) << 3));
      o[f] = MFMA_F16(paP, bv, o[f]);
    }
  }

  float inv[4];
#pragma unroll
  for (int r = 0; r < 4; ++r) inv[r] = 1.0f / __shfl(l, ((lane >> 2) & 12) + r);
#pragma unroll
  for (int f = 0; f < 16; ++f)
#pragma unroll
    for (int r = 0; r < 4; ++r)
      attn[(size_t)(b * 2048 + q0 + g * 4 + r) * 2048 + h * 256 + f * 16 + lm] =
          (f16)(o[f][r] * inv[r]);
}

// ======================= Spectral v4 (f16 input) =======================
__device__ inline float2 cmul(float2 a, float2 b) {
  return make_float2(a.x * b.x - a.y * b.y, a.x * b.y + a.y * b.x);
}
__device__ inline float2 cmulc(float2 a, float2 b) {
  return make_float2(a.x * b.x + a.y * b.y, a.y * b.x - a.x * b.y);
}
__device__ inline void qcube(float2& w, float2& x, float2& y, float2& z, float2 f) {
  w = cmul(w, f); x = cmul(x, f); y = cmul(y, f); z = cmul(z, f);
  float2 a2 = cmul(w, w);
  float2 sx = cmul(x, x), sy = cmul(y, y), sz = cmul(z, z);
  float2 s = make_float2(sx.x + sy.x + sz.x, sx.y + sy.y + sz.y);
  float2 t3 = make_float2(a2.x - 3.f * s.x, a2.y - 3.f * s.y);
  float2 cf = make_float2(3.f * a2.x - s.x, 3.f * a2.y - s.y);
  w = cmul(w, t3); x = cmul(cf, x); y = cmul(cf, y); z = cmul(cf, z);
}

__device__ inline int fftpos(int k) {
  int kp = k >> 1;
  return ((k & 1) << 10) | ((kp & 3) << 8) | ((kp & 12) << 4) | (kp & 48)
       | ((kp >> 4) & 12) | ((kp >> 8) & 3);
}

__global__ __launch_bounds__(256)
void spectral4(const f16* __restrict__ chol, const float* __restrict__ xin,
               float* __restrict__ outp) {
  __shared__ __align__(16) float2 Z[2][2048];
  __shared__ float2 tw[1024];
  const int tid = threadIdx.x;
  const int b = blockIdx.x >> 8;
  const int qd = blockIdx.x & 255;
  const size_t c0 = (size_t)qd * 4;
  const f16* cb = chol + (size_t)b * 2048 * 1024;

  for (int j = tid; j < 1024; j += 256) {
    float ang = -6.2831853071795864769f * (float)j * (1.0f / 2048.0f);
    float sv, cv; sincosf(ang, &sv, &cv);
    tw[j] = make_float2(cv, sv);
  }
  for (int s = tid; s < 2048; s += 256) {
    half4 v = *(const half4*)(cb + (size_t)s * 1024 + c0);
    Z[0][s] = make_float2((float)v[0], (float)v[1]);
    Z[1][s] = make_float2((float)v[2], (float)v[3]);
  }
  __syncthreads();

#pragma unroll 1
  for (int it = 0; it < 8; ++it) {
    int gg = it * 256 + tid;
    int c = gg >> 10, j = gg & 1023;
    float2 a = Z[c][j], bb = Z[c][j + 1024];
    Z[c][j] = make_float2(a.x + bb.x, a.y + bb.y);
    Z[c][j + 1024] = cmul(make_float2(a.x - bb.x, a.y - bb.y), tw[j]);
  }
  __syncthreads();

#pragma unroll 1
  for (int lq = 8; lq >= 0; lq -= 2) {
    const int Q = 1 << lq, st = 512 >> lq;
#pragma unroll 1
    for (int it = 0; it < 4; ++it) {
      int gg = it * 256 + tid;
      int c = gg >> 9, bf = gg & 511;
      int j = bf & (Q - 1);
      int base = ((bf >> lq) << (lq + 2)) | j;
      float2 a = Z[c][base], bq = Z[c][base + Q];
      float2 cc = Z[c][base + 2 * Q], d = Z[c][base + 3 * Q];
      float2 t0 = make_float2(a.x + cc.x, a.y + cc.y);
      float2 t1 = make_float2(a.x - cc.x, a.y - cc.y);
      float2 t2 = make_float2(bq.x + d.x, bq.y + d.y);
      float2 bd = make_float2(bq.x - d.x, bq.y - d.y);
      float2 t3 = make_float2(bd.y, -bd.x);
      float2 y0 = make_float2(t0.x + t2.x, t0.y + t2.y);
      float2 y1 = make_float2(t1.x + t3.x, t1.y + t3.y);
      float2 y2 = make_float2(t0.x - t2.x, t0.y - t2.y);
      float2 y3 = make_float2(t1.x - t3.x, t1.y - t3.y);
      int i3 = 3 * j * st;
      float sg = (i3 & 1024) ? -1.f : 1.f;
      i3 &= 1023;
      Z[c][base] = y0;
      Z[c][base + Q] = cmul(y1, tw[j * st]);
      Z[c][base + 2 * Q] = cmul(y2, tw[2 * j * st]);
      float2 r3 = cmul(y3, tw[i3]);
      Z[c][base + 3 * Q] = make_float2(r3.x * sg, r3.y * sg);
    }
    __syncthreads();
  }

#pragma unroll 1
  for (int it = 0; it < 4; ++it) {
    int jj = it * 256 + tid;
    int nrep = (jj == 0) ? 2 : 1;
#pragma unroll 1
    for (int rep = 0; rep < nrep; ++rep) {
      int k  = (jj == 0) ? (rep ? 1024 : 0) : jj;
      int kn = (jj == 0) ? k : 2048 - jj;
      int p  = fftpos(k);
      int pp = fftpos(kn);
      float2 z0p = Z[0][p], z0q = Z[0][pp];
      float2 z1p = Z[1][p], z1q = Z[1][pp];
      float2 wk = make_float2(0.5f * (z0p.x + z0q.x), 0.5f * (z0p.y - z0q.y));
      float2 xk = make_float2(0.5f * (z0p.y + z0q.y), 0.5f * (z0q.x - z0p.x));
      float2 yk = make_float2(0.5f * (z1p.x + z1q.x), 0.5f * (z1p.y - z1q.y));
      float2 zk = make_float2(0.5f * (z1p.y + z1q.y), 0.5f * (z1q.x - z1p.x));
      float2 wn = make_float2(0.5f * (z0q.x + z0p.x), 0.5f * (z0q.y - z0p.y));
      float2 xn = make_float2(0.5f * (z0q.y + z0p.y), 0.5f * (z0p.x - z0q.x));
      float2 yn = make_float2(0.5f * (z1q.x + z1p.x), 0.5f * (z1q.y - z1p.y));
      float2 zn = make_float2(0.5f * (z1q.y + z1p.y), 0.5f * (z1p.x - z1q.x));
      float sk, ck, sn, cn;
      sincosf(1.5f * atanf(logf((float)k + 1e-10f)), &sk, &ck);
      sincosf(1.5f * atanf(logf((float)kn + 1e-10f)), &sn, &cn);
      qcube(wk, xk, yk, zk, make_float2(ck, sk));
      qcube(wn, xn, yn, zn, make_float2(cn, sn));
      Z[0][p]  = make_float2(0.5f * (wk.x + wn.x) - 0.5f * (xk.y - xn.y),
                             0.5f * (wk.y - wn.y) + 0.5f * (xk.x + xn.x));
      Z[0][pp] = make_float2(0.5f * (wn.x + wk.x) - 0.5f * (xn.y - xk.y),
                             0.5f * (wn.y - wk.y) + 0.5f * (xn.x + xk.x));
      Z[1][p]  = make_float2(0.5f * (yk.x + yn.x) - 0.5f * (zk.y - zn.y),
                             0.5f * (yk.y - yn.y) + 0.5f * (zk.x + zn.x));
      Z[1][pp] = make_float2(0.5f * (yn.x + yk.x) - 0.5f * (zn.y - zk.y),
                             0.5f * (yn.y - yk.y) + 0.5f * (zn.x + zk.x));
    }
  }
  __syncthreads();

#pragma unroll 1
  for (int lq = 0; lq <= 8; lq += 2) {
    const int Q = 1 << lq, st = 512 >> lq;
#pragma unroll 1
    for (int it = 0; it < 4; ++it) {
      int gg = it * 256 + tid;
      int c = gg >> 9, bf = gg & 511;
      int j = bf & (Q - 1);
      int base = ((bf >> lq) << (lq + 2)) | j;
      float2 a = Z[c][base];
      float2 bq = cmulc(Z[c][base + Q], tw[j * st]);
      float2 cc = cmulc(Z[c][base + 2 * Q], tw[2 * j * st]);
      int i3 = 3 * j * st;
      float sg = (i3 & 1024) ? -1.f : 1.f;
      i3 &= 1023;
      float2 d = cmulc(Z[c][base + 3 * Q], tw[i3]);
      d = make_float2(d.x * sg, d.y * sg);
      float2 t0 = make_float2(a.x + cc.x, a.y + cc.y);
      float2 t1 = make_float2(a.x - cc.x, a.y - cc.y);
      float2 t2 = make_float2(bq.x + d.x, bq.y + d.y);
      float2 bd = make_float2(bq.x - d.x, bq.y - d.y);
      float2 t3 = make_float2(-bd.y, bd.x);
      Z[c][base]         = make_float2(t0.x + t2.x, t0.y + t2.y);
      Z[c][base + Q]     = make_float2(t1.x + t3.x, t1.y + t3.y);
      Z[c][base + 2 * Q] = make_float2(t0.x - t2.x, t0.y - t2.y);
      Z[c][base + 3 * Q] = make_float2(t1.x - t3.x, t1.y - t3.y);
    }
    __syncthreads();
  }

#pragma unroll 1
  for (int it = 0; it < 8; ++it) {
    int gg = it * 256 + tid;
    int c = gg >> 10, j = gg & 1023;
    float2 a = Z[c][j];
    float2 bw = cmulc(Z[c][j + 1024], tw[j]);
    Z[c][j] = make_float2(a.x + bw.x, a.y + bw.y);
    Z[c][j + 1024] = make_float2(a.x - bw.x, a.y - bw.y);
  }
  __syncthreads();

  const float* xb = xin + (size_t)b * 2048 * 1024;
  float* ob = outp + (size_t)b * 2048 * 1024;
  const float inv = 1.0f / 2048.0f;
  for (int s = tid; s < 2048; s += 256) {
    float4 xv = *(const float4*)(xb + (size_t)s * 1024 + c0);
    float2 r0 = Z[0][s], r1 = Z[1][s];
    float4 o;
    o.x = xv.x * r0.x * inv;
    o.y = xv.y * r0.y * inv;
    o.z = xv.z * r1.x * inv;
    o.w = xv.w * r1.y * inv;
    *(float4*)(ob + (size_t)s * 1024 + c0) = o;
  }
}

// ======================= launch =======================
extern "C" void kernel_launch(void* const* d_in, const int* in_sizes, int n_in,
                              void* d_out, int out_size, void* d_ws, size_t ws_size,
                              hipStream_t stream) {
  const float* x    = (const float*)d_in[0];
  const float* wqkv = (const float*)d_in[1];
  const float* bqkv = (const float*)d_in[2];
  const float* wout = (const float*)d_in[3];
  const float* bout = (const float*)d_in[4];
  const float* w1   = (const float*)d_in[5];
  const float* b1   = (const float*)d_in[6];
  const float* w2   = (const float*)d_in[7];
  const float* b2   = (const float*)d_in[8];
  float* out = (float*)d_out;
  char* wsb = (char*)d_ws;
  const size_t MB = 1048576;

  f16*   xf    = (f16*)(wsb);
  f16*   wqf   = (f16*)(wsb + 16 * MB);      // rows 0..4095 (Wqkv then W1)
  f16*   wcat  = (f16*)(wsb + 24 * MB);      // [1024][2048]: 1.8*Wout | 0.2*W2
  f16*   qkvF  = (f16*)(wsb + 32 * MB);
  f16*   VtF   = (f16*)(wsb + 80 * MB);
  f16*   cat   = (f16*)(wsb + 96 * MB);
  f16*   chol  = (f16*)(wsb + 128 * MB);

  conv_all<<<7168, 256, 0, stream>>>(x, wqkv, w1, wout, w2, xf);

  // GEMM A: [qkv | gelu(h)] = xf @ [Wqkv;W1]^T  (N=4096, K=1024); V written transposed to VtF
  gemm_f16<3><<<dim3(32, 64), 256, 0, stream>>>(xf, wqf, bqkv, b1, qkvF, cat, VtF, 4096, 1024);
  flash_f16<<<256, 512, 0, stream>>>(qkvF, VtF, cat);   // writes cat low half
  // GEMM B: chol2 = [attn|h] @ [1.8Wout|0.2W2]^T + 1.8bout + 0.2b2  (N=1024, K=2048, f16 out)
  gemm_f16<4><<<dim3(8, 64), 256, 0, stream>>>(cat, wcat, bout, b2, chol, nullptr, nullptr, 1024, 2048);
  spectral4<<<1024, 256, 0, stream>>>(chol, x, out);
}